// Round 7
// baseline (657.817 us; speedup 1.0000x reference)
//
#include <hip/hip_runtime.h>

#define N_NODES 65536
#define N_EDGES 1048576
#define NB      512

typedef unsigned short u16;
typedef unsigned int   u32;
typedef unsigned long long u64;

__device__ __forceinline__ float bf2f(u16 u) { return __uint_as_float(((u32)u) << 16); }
__device__ __forceinline__ float lo16(u32 u) { return __uint_as_float(u << 16); }
__device__ __forceinline__ float hi16(u32 u) { return __uint_as_float(u & 0xffff0000u); }
__device__ __forceinline__ u16 f2bf(float f) {
    u32 u = __float_as_uint(f);
    u32 r = (u + 0x7fffu + ((u >> 16) & 1u)) >> 16;
    return (u16)r;
}
__device__ __forceinline__ float wsum(float v) {
    for (int o = 32; o; o >>= 1) v += __shfl_xor(v, o, 64);
    return v;
}
__device__ __forceinline__ float wmax(float v) {
    for (int o = 32; o; o >>= 1) v = fmaxf(v, __shfl_xor(v, o, 64));
    return v;
}

// ---------- tiny precompute ----------
__global__ void k_prep(const float* g1We, const float* g1ae, const float* g2We, const float* g2ae,
                       float* M1, float* M2) {
    int t = threadIdx.x;
    if (t < 20) {
        int j = t >> 2, h = t & 3;
        float s = 0.f;
        for (int c = 0; c < 64; c++) s += g1We[j * 256 + h * 64 + c] * g1ae[h * 64 + c];
        M1[t] = s;
    } else if (t < 25) {
        int j = t - 20;
        float s = 0.f;
        for (int c = 0; c < 64; c++) s += g2We[j * 64 + c] * g2ae[c];
        M2[j] = s;
    }
}

// ---------- scene ----------
__global__ __launch_bounds__(256) void k_scene(const float* __restrict__ gf, const float* __restrict__ W,
                                               const float* __restrict__ bias, float* __restrict__ scene) {
    int idx = blockIdx.x * 256 + threadIdx.x;
    int b = idx >> 7, j = idx & 127;
    float acc = 0.f;
    for (int k = 0; k < 512; k++) acc += gf[b * 512 + k] * W[k * 128 + j];
    scene[idx] = acc + bias[j];
}

// ---------- histogram ----------
__global__ __launch_bounds__(256) void k_hist(const int* ei, int* cnt) {
    int e = blockIdx.x * 256 + threadIdx.x;
    atomicAdd(&cnt[ei[N_EDGES + e]], 1);
}

// ---------- hierarchical exclusive scan ----------
__global__ __launch_bounds__(256) void k_scan_blk(const int* __restrict__ cnt, int* __restrict__ pre,
                                                  int* __restrict__ bsum) {
    __shared__ int sd[256];
    int t = threadIdx.x, b = blockIdx.x;
    int base = b * 1024 + t * 4;
    int4 c = *(const int4*)(cnt + base);
    int s = c.x + c.y + c.z + c.w;
    sd[t] = s;
    __syncthreads();
    for (int off = 1; off < 256; off <<= 1) {
        int v = (t >= off) ? sd[t - off] : 0;
        __syncthreads();
        sd[t] += v;
        __syncthreads();
    }
    int excl = sd[t] - s;
    int4 p;
    p.x = excl;
    p.y = excl + c.x;
    p.z = excl + c.x + c.y;
    p.w = excl + c.x + c.y + c.z;
    *(int4*)(pre + base) = p;
    if (t == 255) bsum[b] = sd[255];
}

__global__ __launch_bounds__(64) void k_scan_top(int* bsum) {
    int t = threadIdx.x;
    int v = bsum[t];
    int inc = v;
    for (int off = 1; off < 64; off <<= 1) {
        int u = __shfl_up(inc, off, 64);
        if (t >= off) inc += u;
    }
    bsum[t] = inc - v;
}

__global__ __launch_bounds__(256) void k_scan_fix(const int* __restrict__ pre, const int* __restrict__ bsum,
                                                  int* __restrict__ row_ptr, int* __restrict__ coarse_cur) {
    int i = blockIdx.x * 256 + threadIdx.x;
    int v = pre[i] + bsum[i >> 10];
    row_ptr[i] = v;
    if ((i & 255) == 0) coarse_cur[i >> 8] = v;
    if (i == 0) row_ptr[N_NODES] = N_EDGES;
}

// ---------- bucket pass: 256 coarse buckets (dst>>8), run-formed coalesced output ----------
__global__ __launch_bounds__(256) void k_bucket(const int* __restrict__ ei, int* coarse_cur,
                                                u32* __restrict__ bpack, int* __restrict__ bsrc) {
    __shared__ u32 stageP[4096];
    __shared__ int stageS[4096];
    __shared__ int bcnt[256], bscan[256], boff[256], gbase[256];
    int t = threadIdx.x;
    int e0 = blockIdx.x * 4096;
    bcnt[t] = 0;
    __syncthreads();
    int dreg[16], sreg[16];
    for (int it = 0; it < 16; it++) {
        int e = e0 + it * 256 + t;
        int dd = ei[N_EDGES + e];
        dreg[it] = dd;
        sreg[it] = ei[e];
        atomicAdd(&bcnt[dd >> 8], 1);
    }
    __syncthreads();
    int v = bcnt[t];
    bscan[t] = v;
    __syncthreads();
    for (int off = 1; off < 256; off <<= 1) {
        int u = (t >= off) ? bscan[t - off] : 0;
        __syncthreads();
        bscan[t] += u;
        __syncthreads();
    }
    boff[t] = bscan[t] - v;
    gbase[t] = v ? atomicAdd(&coarse_cur[t], v) : 0;
    __syncthreads();
    for (int it = 0; it < 16; it++) {
        int e = e0 + it * 256 + t;
        int b = dreg[it] >> 8;
        int pos = atomicAdd(&boff[b], 1);
        stageP[pos] = ((u32)e << 12) | (u32)(dreg[it] & 255);
        stageS[pos] = sreg[it];
    }
    __syncthreads();
    for (int idx = t; idx < 4096; idx += 256) {
        int lo = 0, hi = 255;
        while (lo < hi) { int mid = (lo + hi) >> 1; if (bscan[mid] > idx) hi = mid; else lo = mid + 1; }
        int b = lo;
        int g = gbase[b] + (idx - (bscan[b] - bcnt[b]));
        bpack[g] = stageP[idx];
        bsrc[g] = stageS[idx];
    }
}

// ---------- local sort within bucket ----------
__global__ __launch_bounds__(256) void k_sortb(const u32* __restrict__ bpack, const int* __restrict__ bsrc,
                                               const int* __restrict__ row_ptr,
                                               int* __restrict__ eord, int* __restrict__ ssrc) {
    __shared__ int cur[256];
    int t = threadIdx.x, b = blockIdx.x;
    int nbase = b * 256;
    cur[t] = row_ptr[nbase + t];
    __syncthreads();
    int beg = row_ptr[nbase];
    int end = row_ptr[nbase + 256];
    for (int i = beg + t; i < end; i += 256) {
        u32 wd = bpack[i];
        int src = bsrc[i];
        int d8 = wd & 255;
        int pos = atomicAdd(&cur[d8], 1);
        eord[pos] = (int)(wd >> 12);
        ssrc[pos] = src;
    }
}

// ---------- payload in pos order ----------
__global__ __launch_bounds__(256) void k_payload(const int* __restrict__ eord, const float* __restrict__ ea,
                                                 const float* __restrict__ M1, const float* __restrict__ M2,
                                                 float* __restrict__ a1es, float* __restrict__ a2es) {
    int pos = blockIdx.x * 256 + threadIdx.x;
    int e = eord[pos];
    float v[5];
    for (int j = 0; j < 5; j++) v[j] = ea[(size_t)e * 5 + j];
    float4 o;
    o.x = v[0]*M1[0]  + v[1]*M1[4]  + v[2]*M1[8]  + v[3]*M1[12] + v[4]*M1[16];
    o.y = v[0]*M1[1]  + v[1]*M1[5]  + v[2]*M1[9]  + v[3]*M1[13] + v[4]*M1[17];
    o.z = v[0]*M1[2]  + v[1]*M1[6]  + v[2]*M1[10] + v[3]*M1[14] + v[4]*M1[18];
    o.w = v[0]*M1[3]  + v[1]*M1[7]  + v[2]*M1[11] + v[3]*M1[15] + v[4]*M1[19];
    *(float4*)(a1es + (size_t)pos * 4) = o;
    a2es[pos] = v[0]*M2[0] + v[1]*M2[1] + v[2]*M2[2] + v[3]*M2[3] + v[4]*M2[4];
}

// ---------- register-blocked GEMM: vis = relu(roi @ roiW + b) ----------
__global__ __launch_bounds__(256) void k_vis(const float* __restrict__ A, const float* __restrict__ W,
                                             const float* __restrict__ bias, float* __restrict__ out) {
    __shared__ float At[64][68];
    __shared__ float Wl[64][68];
    int t = threadIdx.x;
    int n0 = blockIdx.x * 64;
    int cg = t & 15, rg = t >> 4;
    int sr = t >> 2, scs = (t & 3) * 16;
    float acc[4][4];
    for (int i = 0; i < 4; i++) for (int j = 0; j < 4; j++) acc[i][j] = 0.f;
    for (int kc = 0; kc < 4; kc++) {
        __syncthreads();
        const float* ap = A + (size_t)(n0 + sr) * 256 + kc * 64 + scs;
        float4 q0 = *(const float4*)ap, q1 = *(const float4*)(ap + 4);
        float4 q2 = *(const float4*)(ap + 8), q3 = *(const float4*)(ap + 12);
        At[scs + 0][sr] = q0.x;  At[scs + 1][sr] = q0.y;  At[scs + 2][sr] = q0.z;  At[scs + 3][sr] = q0.w;
        At[scs + 4][sr] = q1.x;  At[scs + 5][sr] = q1.y;  At[scs + 6][sr] = q1.z;  At[scs + 7][sr] = q1.w;
        At[scs + 8][sr] = q2.x;  At[scs + 9][sr] = q2.y;  At[scs + 10][sr] = q2.z; At[scs + 11][sr] = q2.w;
        At[scs + 12][sr] = q3.x; At[scs + 13][sr] = q3.y; At[scs + 14][sr] = q3.z; At[scs + 15][sr] = q3.w;
        const float* wp = W + (size_t)(kc * 64 + sr) * 64 + scs;
        *(float4*)&Wl[sr][scs + 0]  = *(const float4*)wp;
        *(float4*)&Wl[sr][scs + 4]  = *(const float4*)(wp + 4);
        *(float4*)&Wl[sr][scs + 8]  = *(const float4*)(wp + 8);
        *(float4*)&Wl[sr][scs + 12] = *(const float4*)(wp + 12);
        __syncthreads();
        for (int k = 0; k < 64; k++) {
            float4 a4 = *(const float4*)&At[k][rg * 4];
            float4 w4 = *(const float4*)&Wl[k][cg * 4];
            acc[0][0] += a4.x * w4.x; acc[0][1] += a4.x * w4.y; acc[0][2] += a4.x * w4.z; acc[0][3] += a4.x * w4.w;
            acc[1][0] += a4.y * w4.x; acc[1][1] += a4.y * w4.y; acc[1][2] += a4.y * w4.z; acc[1][3] += a4.y * w4.w;
            acc[2][0] += a4.z * w4.x; acc[2][1] += a4.z * w4.y; acc[2][2] += a4.z * w4.z; acc[2][3] += a4.z * w4.w;
            acc[3][0] += a4.w * w4.x; acc[3][1] += a4.w * w4.y; acc[3][2] += a4.w * w4.z; acc[3][3] += a4.w * w4.w;
        }
    }
    float4 bb = *(const float4*)(bias + cg * 4);
    for (int i = 0; i < 4; i++) {
        float4 o;
        o.x = fmaxf(acc[i][0] + bb.x, 0.f);
        o.y = fmaxf(acc[i][1] + bb.y, 0.f);
        o.z = fmaxf(acc[i][2] + bb.z, 0.f);
        o.w = fmaxf(acc[i][3] + bb.w, 0.f);
        *(float4*)(out + (size_t)(n0 + rg * 4 + i) * 64 + cg * 4) = o;
    }
}

// ---------- register-blocked GEMM: h2 = out1(bf16) @ g2W -> bf16 ----------
__global__ __launch_bounds__(256) void k_h2(const u16* __restrict__ A, const float* __restrict__ W,
                                            u16* __restrict__ out) {
    __shared__ float At[64][68];
    __shared__ float Wl[64][68];
    int t = threadIdx.x;
    int n0 = blockIdx.x * 64;
    int cg = t & 15, rg = t >> 4;
    int sr = t >> 2, scs = (t & 3) * 16;
    float acc[4][4];
    for (int i = 0; i < 4; i++) for (int j = 0; j < 4; j++) acc[i][j] = 0.f;
    for (int kc = 0; kc < 4; kc++) {
        __syncthreads();
        const u16* ap = A + (size_t)(n0 + sr) * 256 + kc * 64 + scs;
        uint4 u0 = *(const uint4*)ap;
        uint4 u1 = *(const uint4*)(ap + 8);
        At[scs + 0][sr] = lo16(u0.x);  At[scs + 1][sr] = hi16(u0.x);
        At[scs + 2][sr] = lo16(u0.y);  At[scs + 3][sr] = hi16(u0.y);
        At[scs + 4][sr] = lo16(u0.z);  At[scs + 5][sr] = hi16(u0.z);
        At[scs + 6][sr] = lo16(u0.w);  At[scs + 7][sr] = hi16(u0.w);
        At[scs + 8][sr] = lo16(u1.x);  At[scs + 9][sr] = hi16(u1.x);
        At[scs + 10][sr] = lo16(u1.y); At[scs + 11][sr] = hi16(u1.y);
        At[scs + 12][sr] = lo16(u1.z); At[scs + 13][sr] = hi16(u1.z);
        At[scs + 14][sr] = lo16(u1.w); At[scs + 15][sr] = hi16(u1.w);
        const float* wp = W + (size_t)(kc * 64 + sr) * 64 + scs;
        *(float4*)&Wl[sr][scs + 0]  = *(const float4*)wp;
        *(float4*)&Wl[sr][scs + 4]  = *(const float4*)(wp + 4);
        *(float4*)&Wl[sr][scs + 8]  = *(const float4*)(wp + 8);
        *(float4*)&Wl[sr][scs + 12] = *(const float4*)(wp + 12);
        __syncthreads();
        for (int k = 0; k < 64; k++) {
            float4 a4 = *(const float4*)&At[k][rg * 4];
            float4 w4 = *(const float4*)&Wl[k][cg * 4];
            acc[0][0] += a4.x * w4.x; acc[0][1] += a4.x * w4.y; acc[0][2] += a4.x * w4.z; acc[0][3] += a4.x * w4.w;
            acc[1][0] += a4.y * w4.x; acc[1][1] += a4.y * w4.y; acc[1][2] += a4.y * w4.z; acc[1][3] += a4.y * w4.w;
            acc[2][0] += a4.z * w4.x; acc[2][1] += a4.z * w4.y; acc[2][2] += a4.z * w4.z; acc[2][3] += a4.z * w4.w;
            acc[3][0] += a4.w * w4.x; acc[3][1] += a4.w * w4.y; acc[3][2] += a4.w * w4.z; acc[3][3] += a4.w * w4.w;
        }
    }
    u32* outu = (u32*)out;
    for (int i = 0; i < 4; i++) {
        uint2 pk;
        pk.x = (u32)f2bf(acc[i][0]) | ((u32)f2bf(acc[i][1]) << 16);
        pk.y = (u32)f2bf(acc[i][2]) | ((u32)f2bf(acc[i][3]) << 16);
        *(uint2*)(outu + (size_t)(n0 + rg * 4 + i) * 32 + cg * 2) = pk;
    }
}

// ---------- h1 = [x | vis] @ g1_W ----------
__global__ __launch_bounds__(256) void k_h1(const float* __restrict__ x, const float* __restrict__ vis,
                                            const float* __restrict__ g1W, u16* __restrict__ h1) {
    __shared__ float At[77][36];
    __shared__ float Wl[77][132];
    int t = threadIdx.x, ch = blockIdx.y;
    int n0 = blockIdx.x * 32;
    int cg = t & 31, rg = t >> 5;
    for (int idx = t; idx < 9856; idx += 256) {
        int k = idx >> 7, c = idx & 127;
        Wl[k][c] = g1W[(size_t)k * 256 + ch * 128 + c];
    }
    for (int idx = t; idx < 2464; idx += 256) {
        int r = idx / 77, k = idx - r * 77;
        At[k][r] = (k < 13) ? x[(size_t)(n0 + r) * 13 + k] : vis[(size_t)(n0 + r) * 64 + (k - 13)];
    }
    __syncthreads();
    float acc[4][4];
    for (int i = 0; i < 4; i++) for (int j = 0; j < 4; j++) acc[i][j] = 0.f;
    for (int k = 0; k < 77; k++) {
        float4 a4 = *(const float4*)&At[k][rg * 4];
        float4 w4 = *(const float4*)&Wl[k][cg * 4];
        acc[0][0] += a4.x * w4.x; acc[0][1] += a4.x * w4.y; acc[0][2] += a4.x * w4.z; acc[0][3] += a4.x * w4.w;
        acc[1][0] += a4.y * w4.x; acc[1][1] += a4.y * w4.y; acc[1][2] += a4.y * w4.z; acc[1][3] += a4.y * w4.w;
        acc[2][0] += a4.z * w4.x; acc[2][1] += a4.z * w4.y; acc[2][2] += a4.z * w4.z; acc[2][3] += a4.z * w4.w;
        acc[3][0] += a4.w * w4.x; acc[3][1] += a4.w * w4.y; acc[3][2] += a4.w * w4.z; acc[3][3] += a4.w * w4.w;
    }
    for (int i = 0; i < 4; i++) {
        uint2 pk;
        pk.x = (u32)f2bf(acc[i][0]) | ((u32)f2bf(acc[i][1]) << 16);
        pk.y = (u32)f2bf(acc[i][2]) | ((u32)f2bf(acc[i][3]) << 16);
        *(uint2*)(h1 + (size_t)(n0 + rg * 4 + i) * 256 + ch * 128 + cg * 4) = pk;
    }
}

// ---------- a1_s/a1_d ----------
__global__ __launch_bounds__(256) void k_a1(const u16* __restrict__ h1, const float* __restrict__ as_,
                                            const float* __restrict__ ad_, float* a1s, float* a1d) {
    int t = threadIdx.x;
    int w = t >> 6, L = t & 63;
    float4 as4 = *(const float4*)(as_ + 4 * L);
    float4 ad4 = *(const float4*)(ad_ + 4 * L);
    int base = (blockIdx.x * 4 + w) * 16;
    for (int j = 0; j < 16; j++) {
        int n = base + j;
        uint2 u = *((const uint2*)(h1 + (size_t)n * 256) + L);
        float v0 = lo16(u.x), v1 = hi16(u.x), v2 = lo16(u.y), v3 = hi16(u.y);
        float ps = v0 * as4.x + v1 * as4.y + v2 * as4.z + v3 * as4.w;
        float pd = v0 * ad4.x + v1 * ad4.y + v2 * ad4.z + v3 * ad4.w;
        for (int o = 1; o < 16; o <<= 1) { ps += __shfl_xor(ps, o, 64); pd += __shfl_xor(pd, o, 64); }
        if ((L & 15) == 0) {
            a1s[n * 4 + (L >> 4)] = ps;
            a1d[n * 4 + (L >> 4)] = pd;
        }
    }
}

__global__ __launch_bounds__(256) void k_a2(const u16* __restrict__ h2b, const float* __restrict__ as_,
                                            const float* __restrict__ ad_, float* a2s, float* a2d) {
    int t = threadIdx.x;
    int w = t >> 6, lane = t & 63;
    int n = blockIdx.x * 4 + w;
    float v = bf2f(h2b[(size_t)n * 64 + lane]);
    float ps = wsum(v * as_[lane]);
    float pd = wsum(v * ad_[lane]);
    if (lane == 0) { a2s[n] = ps; a2d[n] = pd; }
}

// ---------- GAT1 softmax: wave per node, 16-lane group per head ----------
__global__ __launch_bounds__(256) void k_soft1(const int* __restrict__ row_ptr, const int* __restrict__ ssrc,
                                               const float* __restrict__ a1s, const float* __restrict__ a1d,
                                               const float* __restrict__ a1es, float* __restrict__ w1) {
    int t = threadIdx.x;
    int wv = t >> 6, L = t & 63;
    int n = blockIdx.x * 4 + wv;
    int h = L >> 4, j = L & 15;
    int beg = row_ptr[n], deg = row_ptr[n + 1] - beg;
    if (deg == 0) return;
    float adn = a1d[n * 4 + h];
    float m = -3.0e38f, s = 0.f;
    for (int i = j; i < deg; i += 16) {
        int pos = beg + i;
        float l = a1s[ssrc[pos] * 4 + h] + adn + a1es[(size_t)pos * 4 + h];
        l = (l > 0.f) ? l : 0.2f * l;
        if (l > m) { s = s * __expf(m - l) + 1.f; m = l; }
        else       { s += __expf(l - m); }
    }
    for (int o = 1; o < 16; o <<= 1) {
        float mo = __shfl_xor(m, o, 64), so = __shfl_xor(s, o, 64);
        float M = fmaxf(m, mo);
        s = s * __expf(m - M) + so * __expf(mo - M);
        m = M;
    }
    float inv = 1.f / (s + 1e-16f);
    for (int i = j; i < deg; i += 16) {
        int pos = beg + i;
        float l = a1s[ssrc[pos] * 4 + h] + adn + a1es[(size_t)pos * 4 + h];
        l = (l > 0.f) ? l : 0.2f * l;
        w1[(size_t)pos * 4 + h] = __expf(l - m) * inv;
    }
}

// ---------- GAT1 gather: wave per node; lane-cooperative metadata + shfl ----------
__global__ __launch_bounds__(256) void k_gath1(const int* __restrict__ row_ptr, const int* __restrict__ ssrc,
                                               const float* __restrict__ w1, const u16* __restrict__ h1,
                                               const float* __restrict__ bias, u16* __restrict__ out1) {
    int t = threadIdx.x;
    int wv = t >> 6, L = t & 63;
    int n = blockIdx.x * 4 + wv;
    int beg = row_ptr[n], deg = row_ptr[n + 1] - beg;
    int hd = L >> 4, j16 = L & 15;
    float a0 = 0.f, a1v = 0.f, a2v = 0.f, a3v = 0.f;
    int base = 0;
    // full 16-edge chunks
    for (; base + 16 <= deg; base += 16) {
        int idx = beg + base + j16;
        int src_r = ssrc[idx];
        float w_r = w1[(size_t)idx * 4 + hd];      // lane (hd,j16) holds w of edge j16, head hd
        #pragma unroll
        for (int j = 0; j < 16; j++) {
            int src = __shfl(src_r, j, 64);
            float wgt = __shfl(w_r, hd * 16 + j, 64);
            uint2 ua = *((const uint2*)(h1 + (size_t)src * 256) + L);
            a0  += wgt * lo16(ua.x);
            a1v += wgt * hi16(ua.x);
            a2v += wgt * lo16(ua.y);
            a3v += wgt * hi16(ua.y);
        }
    }
    // tail
    int cnt = deg - base;
    if (cnt > 0) {
        int idx = beg + base + j16;
        int src_r = 0; float w_r = 0.f;
        if (j16 < cnt) {
            src_r = ssrc[idx];
            w_r = w1[(size_t)idx * 4 + hd];
        }
        for (int j = 0; j < cnt; j++) {
            int src = __shfl(src_r, j, 64);
            float wgt = __shfl(w_r, hd * 16 + j, 64);
            uint2 ua = *((const uint2*)(h1 + (size_t)src * 256) + L);
            a0  += wgt * lo16(ua.x);
            a1v += wgt * hi16(ua.x);
            a2v += wgt * lo16(ua.y);
            a3v += wgt * hi16(ua.y);
        }
    }
    float4 bb = *(const float4*)(bias + 4 * L);
    uint2 pk;
    pk.x = (u32)f2bf(fmaxf(a0 + bb.x, 0.f)) | ((u32)f2bf(fmaxf(a1v + bb.y, 0.f)) << 16);
    pk.y = (u32)f2bf(fmaxf(a2v + bb.z, 0.f)) | ((u32)f2bf(fmaxf(a3v + bb.w, 0.f)) << 16);
    *((uint2*)(out1 + (size_t)n * 256) + L) = pk;
}

// ---------- GAT2 softmax ----------
__global__ __launch_bounds__(256) void k_soft2(const int* __restrict__ row_ptr, const int* __restrict__ ssrc,
                                               const float* __restrict__ a2s, const float* __restrict__ a2d,
                                               const float* __restrict__ a2es, float* __restrict__ w2) {
    int t = threadIdx.x;
    int wv = t >> 6, L = t & 63;
    int g = L >> 4, j = L & 15;
    int n = blockIdx.x * 16 + wv * 4 + g;
    int beg = row_ptr[n], deg = row_ptr[n + 1] - beg;
    if (deg == 0) return;
    float adn = a2d[n];
    float m = -3.0e38f, s = 0.f;
    for (int i = j; i < deg; i += 16) {
        int pos = beg + i;
        float l = a2s[ssrc[pos]] + adn + a2es[pos];
        l = (l > 0.f) ? l : 0.2f * l;
        if (l > m) { s = s * __expf(m - l) + 1.f; m = l; }
        else       { s += __expf(l - m); }
    }
    for (int o = 1; o < 16; o <<= 1) {
        float mo = __shfl_xor(m, o, 64), so = __shfl_xor(s, o, 64);
        float M = fmaxf(m, mo);
        s = s * __expf(m - M) + so * __expf(mo - M);
        m = M;
    }
    float inv = 1.f / (s + 1e-16f);
    for (int i = j; i < deg; i += 16) {
        int pos = beg + i;
        float l = a2s[ssrc[pos]] + adn + a2es[pos];
        l = (l > 0.f) ? l : 0.2f * l;
        w2[pos] = __expf(l - m) * inv;
    }
}

// ---------- GAT2 gather: bf16 rows, lane-cooperative metadata + shfl ----------
__global__ __launch_bounds__(256) void k_gath2(const int* __restrict__ row_ptr, const int* __restrict__ ssrc,
                                               const float* __restrict__ w2, const u16* __restrict__ h2b,
                                               const float* __restrict__ bias, float* __restrict__ hfin) {
    int t = threadIdx.x;
    int wv = t >> 6, L = t & 63;
    int n = blockIdx.x * 4 + wv;
    int beg = row_ptr[n], deg = row_ptr[n + 1] - beg;
    float acc = 0.f;
    for (int base = 0; base < deg; base += 64) {
        int cnt = min(64, deg - base);
        int src_r = 0; float w_r = 0.f;
        if (L < cnt) {
            src_r = ssrc[beg + base + L];
            w_r = w2[beg + base + L];
        }
        int j = 0;
        for (; j + 4 <= cnt; j += 4) {
            int s0 = __shfl(src_r, j, 64),     s1 = __shfl(src_r, j + 1, 64);
            int s2 = __shfl(src_r, j + 2, 64), s3 = __shfl(src_r, j + 3, 64);
            float w0 = __shfl(w_r, j, 64),     w1v = __shfl(w_r, j + 1, 64);
            float w2v = __shfl(w_r, j + 2, 64), w3 = __shfl(w_r, j + 3, 64);
            float v0 = bf2f(h2b[(size_t)s0 * 64 + L]);
            float v1 = bf2f(h2b[(size_t)s1 * 64 + L]);
            float v2 = bf2f(h2b[(size_t)s2 * 64 + L]);
            float v3 = bf2f(h2b[(size_t)s3 * 64 + L]);
            acc += w0 * v0 + w1v * v1 + w2v * v2 + w3 * v3;
        }
        for (; j < cnt; j++) {
            int s0 = __shfl(src_r, j, 64);
            float w0 = __shfl(w_r, j, 64);
            acc += w0 * bf2f(h2b[(size_t)s0 * 64 + L]);
        }
    }
    hfin[(size_t)n * 64 + L] = acc + bias[L];
}

// ---------- pooling + classifier ----------
__global__ __launch_bounds__(64) void k_pool(const int* __restrict__ bvec, const float* __restrict__ hf,
                                             const float* gateW, const float* gateb,
                                             const float* __restrict__ scene,
                                             const float* c1W, const float* c1b,
                                             const float* c2W, const float* c2b,
                                             float* __restrict__ outp) {
    int b = blockIdx.x, lane = threadIdx.x;
    __shared__ float gwl[64], se[64], comb[192], hid[64];
    gwl[lane] = gateW[lane];
    __syncthreads();
    int s0, s1;
    { int lo = 0, hi = N_NODES; while (lo < hi) { int mid = (lo + hi) >> 1; if (bvec[mid] < b) lo = mid + 1; else hi = mid; } s0 = lo; }
    { int lo = 0, hi = N_NODES; while (lo < hi) { int mid = (lo + hi) >> 1; if (bvec[mid] < b + 1) lo = mid + 1; else hi = mid; } s1 = lo; }
    float gb = gateb[0];
    float m = -3.0e38f, ssum = 0.f, acc = 0.f;
    for (int cs = s0; cs < s1; cs += 64) {
        int cnt = min(64, s1 - cs);
        float l = -3.0e38f;
        if (lane < cnt) {
            int n = cs + lane;
            float d = 0.f;
            for (int i = 0; i < 64; i++) d += hf[(size_t)n * 64 + i] * gwl[i];
            l = d + gb;
        }
        float cm = wmax(l);
        float newm = fmaxf(m, cm);
        float rsc = __expf(m - newm);
        float e = (lane < cnt) ? __expf(l - newm) : 0.f;
        float es = wsum(e);
        ssum = ssum * rsc + es;
        se[lane] = e;
        __syncthreads();
        float a2 = 0.f;
        for (int i = 0; i < cnt; i++) a2 += se[i] * hf[(size_t)(cs + i) * 64 + lane];
        acc = acc * rsc + a2;
        __syncthreads();
        m = newm;
    }
    float rel = acc / (ssum + 1e-16f);
    comb[lane] = scene[b * 128 + lane];
    comb[64 + lane] = scene[b * 128 + 64 + lane];
    comb[128 + lane] = rel;
    __syncthreads();
    float hj = 0.f;
    for (int k = 0; k < 192; k++) hj += comb[k] * c1W[k * 64 + lane];
    hj += c1b[lane];
    hid[lane] = fmaxf(hj, 0.f);
    __syncthreads();
    if (lane < 3) {
        float o = 0.f;
        for (int k = 0; k < 64; k++) o += hid[k] * c2W[k * 3 + lane];
        o += c2b[lane];
        outp[b * 3 + lane] = o;
    }
}

extern "C" void kernel_launch(void* const* d_in, const int* in_sizes, int n_in,
                              void* d_out, int out_size, void* d_ws, size_t ws_size,
                              hipStream_t stream) {
    (void)in_sizes; (void)n_in; (void)out_size; (void)ws_size;
    const float* gf     = (const float*)d_in[0];
    const float* x      = (const float*)d_in[1];
    const float* roi    = (const float*)d_in[2];
    const int*   ei     = (const int*)d_in[3];
    const float* ea     = (const float*)d_in[4];
    const int*   bvec   = (const int*)d_in[5];
    const float* roiW   = (const float*)d_in[6];
    const float* roib   = (const float*)d_in[7];
    const float* sceneW = (const float*)d_in[8];
    const float* sceneb = (const float*)d_in[9];
    const float* g1W    = (const float*)d_in[10];
    const float* g1as   = (const float*)d_in[11];
    const float* g1ad   = (const float*)d_in[12];
    const float* g1We   = (const float*)d_in[13];
    const float* g1ae   = (const float*)d_in[14];
    const float* g1b    = (const float*)d_in[15];
    const float* g2W    = (const float*)d_in[16];
    const float* g2as   = (const float*)d_in[17];
    const float* g2ad   = (const float*)d_in[18];
    const float* g2We   = (const float*)d_in[19];
    const float* g2ae   = (const float*)d_in[20];
    const float* g2b    = (const float*)d_in[21];
    const float* gateW  = (const float*)d_in[22];
    const float* gateb  = (const float*)d_in[23];
    const float* c1W    = (const float*)d_in[24];
    const float* c1b    = (const float*)d_in[25];
    const float* c2W    = (const float*)d_in[26];
    const float* c2b    = (const float*)d_in[27];

    char* w = (char*)d_ws;
    size_t o = 0;
    auto nxt = [&](size_t bytes) -> char* {
        char* p = w + o;
        o += (bytes + 255) & ~(size_t)255;
        return p;
    };
    float* scene  = (float*)nxt((size_t)NB * 128 * 4);
    float* M1     = (float*)nxt(80);
    float* M2     = (float*)nxt(32);
    int* cnt      = (int*)nxt((size_t)N_NODES * 4);
    int* pre      = (int*)nxt((size_t)N_NODES * 4);
    int* bsum     = (int*)nxt(64 * 4);
    int* row_ptr  = (int*)nxt((size_t)(N_NODES + 1) * 4);
    int* coarse   = (int*)nxt(256 * 4);
    u32* bpack    = (u32*)nxt((size_t)N_EDGES * 4);
    int* bsrc     = (int*)nxt((size_t)N_EDGES * 4);
    int* eord     = (int*)nxt((size_t)N_EDGES * 4);
    int* ssrc     = (int*)nxt((size_t)N_EDGES * 4);
    float* a1es   = (float*)nxt((size_t)N_EDGES * 16);
    float* a2es   = (float*)nxt((size_t)N_EDGES * 4);
    float* visbuf = (float*)nxt((size_t)N_NODES * 64 * 4);   // vis, later aliased as w2
    u16* h1       = (u16*)nxt((size_t)N_NODES * 256 * 2);
    u16* out1     = (u16*)nxt((size_t)N_NODES * 256 * 2);
    float* w1buf  = (float*)nxt((size_t)N_EDGES * 16);       // w1, later aliased as h2(bf16)
    float* hfin   = (float*)nxt((size_t)N_NODES * 64 * 4);
    float* a1s    = (float*)nxt((size_t)N_NODES * 16);
    float* a1d    = (float*)nxt((size_t)N_NODES * 16);
    float* a2s    = (float*)nxt((size_t)N_NODES * 4);
    float* a2d    = (float*)nxt((size_t)N_NODES * 4);

    float* vis = visbuf;
    float* w2  = visbuf;      // vis dead after k_h1; w2 written by k_soft2 (later)
    float* w1  = w1buf;
    u16*   h2b = (u16*)w1buf; // w1 dead after k_gath1; h2(bf16) written by k_h2 (later)

    hipMemsetAsync(cnt, 0, (size_t)N_NODES * 4, stream);
    k_prep<<<1, 32, 0, stream>>>(g1We, g1ae, g2We, g2ae, M1, M2);
    k_scene<<<(NB * 128) / 256, 256, 0, stream>>>(gf, sceneW, sceneb, scene);
    k_hist<<<N_EDGES / 256, 256, 0, stream>>>(ei, cnt);
    k_scan_blk<<<64, 256, 0, stream>>>(cnt, pre, bsum);
    k_scan_top<<<1, 64, 0, stream>>>(bsum);
    k_scan_fix<<<N_NODES / 256, 256, 0, stream>>>(pre, bsum, row_ptr, coarse);
    k_bucket<<<256, 256, 0, stream>>>(ei, coarse, bpack, bsrc);
    k_sortb<<<256, 256, 0, stream>>>(bpack, bsrc, row_ptr, eord, ssrc);
    k_payload<<<N_EDGES / 256, 256, 0, stream>>>(eord, ea, M1, M2, a1es, a2es);
    k_vis<<<N_NODES / 64, 256, 0, stream>>>(roi, roiW, roib, vis);
    k_h1<<<dim3(N_NODES / 32, 2), 256, 0, stream>>>(x, vis, g1W, h1);
    k_a1<<<N_NODES / 64, 256, 0, stream>>>(h1, g1as, g1ad, a1s, a1d);
    k_soft1<<<N_NODES / 4, 256, 0, stream>>>(row_ptr, ssrc, a1s, a1d, a1es, w1);
    k_gath1<<<N_NODES / 4, 256, 0, stream>>>(row_ptr, ssrc, w1, h1, g1b, out1);
    k_h2<<<N_NODES / 64, 256, 0, stream>>>(out1, g2W, h2b);
    k_a2<<<N_NODES / 4, 256, 0, stream>>>(h2b, g2as, g2ad, a2s, a2d);
    k_soft2<<<N_NODES / 16, 256, 0, stream>>>(row_ptr, ssrc, a2s, a2d, a2es, w2);
    k_gath2<<<N_NODES / 4, 256, 0, stream>>>(row_ptr, ssrc, w2, h2b, g2b, hfin);
    k_pool<<<NB, 64, 0, stream>>>(bvec, hfin, gateW, gateb, scene, c1W, c1b, c2W, c2b, (float*)d_out);
}

// Round 8
// 640.872 us; speedup vs baseline: 1.0264x; 1.0264x over previous
//
#include <hip/hip_runtime.h>

#define N_NODES 65536
#define N_EDGES 1048576
#define NB      512

typedef unsigned short u16;
typedef unsigned int   u32;
typedef unsigned long long u64;

__device__ __forceinline__ float bf2f(u16 u) { return __uint_as_float(((u32)u) << 16); }
__device__ __forceinline__ float lo16(u32 u) { return __uint_as_float(u << 16); }
__device__ __forceinline__ float hi16(u32 u) { return __uint_as_float(u & 0xffff0000u); }
__device__ __forceinline__ u16 f2bf(float f) {
    u32 u = __float_as_uint(f);
    u32 r = (u + 0x7fffu + ((u >> 16) & 1u)) >> 16;
    return (u16)r;
}
__device__ __forceinline__ float wsum(float v) {
    for (int o = 32; o; o >>= 1) v += __shfl_xor(v, o, 64);
    return v;
}
__device__ __forceinline__ float wmax(float v) {
    for (int o = 32; o; o >>= 1) v = fmaxf(v, __shfl_xor(v, o, 64));
    return v;
}

// ---------- tiny precompute ----------
__global__ void k_prep(const float* g1We, const float* g1ae, const float* g2We, const float* g2ae,
                       float* M1, float* M2) {
    int t = threadIdx.x;
    if (t < 20) {
        int j = t >> 2, h = t & 3;
        float s = 0.f;
        for (int c = 0; c < 64; c++) s += g1We[j * 256 + h * 64 + c] * g1ae[h * 64 + c];
        M1[t] = s;
    } else if (t < 25) {
        int j = t - 20;
        float s = 0.f;
        for (int c = 0; c < 64; c++) s += g2We[j * 64 + c] * g2ae[c];
        M2[j] = s;
    }
}

// ---------- scene ----------
__global__ __launch_bounds__(256) void k_scene(const float* __restrict__ gf, const float* __restrict__ W,
                                               const float* __restrict__ bias, float* __restrict__ scene) {
    int idx = blockIdx.x * 256 + threadIdx.x;
    int b = idx >> 7, j = idx & 127;
    float acc = 0.f;
    for (int k = 0; k < 512; k++) acc += gf[b * 512 + k] * W[k * 128 + j];
    scene[idx] = acc + bias[j];
}

// ---------- histogram ----------
__global__ __launch_bounds__(256) void k_hist(const int* ei, int* cnt) {
    int e = blockIdx.x * 256 + threadIdx.x;
    atomicAdd(&cnt[ei[N_EDGES + e]], 1);
}

// ---------- hierarchical exclusive scan ----------
__global__ __launch_bounds__(256) void k_scan_blk(const int* __restrict__ cnt, int* __restrict__ pre,
                                                  int* __restrict__ bsum) {
    __shared__ int sd[256];
    int t = threadIdx.x, b = blockIdx.x;
    int base = b * 1024 + t * 4;
    int4 c = *(const int4*)(cnt + base);
    int s = c.x + c.y + c.z + c.w;
    sd[t] = s;
    __syncthreads();
    for (int off = 1; off < 256; off <<= 1) {
        int v = (t >= off) ? sd[t - off] : 0;
        __syncthreads();
        sd[t] += v;
        __syncthreads();
    }
    int excl = sd[t] - s;
    int4 p;
    p.x = excl;
    p.y = excl + c.x;
    p.z = excl + c.x + c.y;
    p.w = excl + c.x + c.y + c.z;
    *(int4*)(pre + base) = p;
    if (t == 255) bsum[b] = sd[255];
}

__global__ __launch_bounds__(64) void k_scan_top(int* bsum) {
    int t = threadIdx.x;
    int v = bsum[t];
    int inc = v;
    for (int off = 1; off < 64; off <<= 1) {
        int u = __shfl_up(inc, off, 64);
        if (t >= off) inc += u;
    }
    bsum[t] = inc - v;
}

__global__ __launch_bounds__(256) void k_scan_fix(const int* __restrict__ pre, const int* __restrict__ bsum,
                                                  int* __restrict__ row_ptr, int* __restrict__ coarse_cur) {
    int i = blockIdx.x * 256 + threadIdx.x;
    int v = pre[i] + bsum[i >> 10];
    row_ptr[i] = v;
    if ((i & 255) == 0) coarse_cur[i >> 8] = v;
    if (i == 0) row_ptr[N_NODES] = N_EDGES;
}

// ---------- bucket pass ----------
__global__ __launch_bounds__(256) void k_bucket(const int* __restrict__ ei, int* coarse_cur,
                                                u32* __restrict__ bpack, int* __restrict__ bsrc) {
    __shared__ u32 stageP[4096];
    __shared__ int stageS[4096];
    __shared__ int bcnt[256], bscan[256], boff[256], gbase[256];
    int t = threadIdx.x;
    int e0 = blockIdx.x * 4096;
    bcnt[t] = 0;
    __syncthreads();
    int dreg[16], sreg[16];
    for (int it = 0; it < 16; it++) {
        int e = e0 + it * 256 + t;
        int dd = ei[N_EDGES + e];
        dreg[it] = dd;
        sreg[it] = ei[e];
        atomicAdd(&bcnt[dd >> 8], 1);
    }
    __syncthreads();
    int v = bcnt[t];
    bscan[t] = v;
    __syncthreads();
    for (int off = 1; off < 256; off <<= 1) {
        int u = (t >= off) ? bscan[t - off] : 0;
        __syncthreads();
        bscan[t] += u;
        __syncthreads();
    }
    boff[t] = bscan[t] - v;
    gbase[t] = v ? atomicAdd(&coarse_cur[t], v) : 0;
    __syncthreads();
    for (int it = 0; it < 16; it++) {
        int e = e0 + it * 256 + t;
        int b = dreg[it] >> 8;
        int pos = atomicAdd(&boff[b], 1);
        stageP[pos] = ((u32)e << 12) | (u32)(dreg[it] & 255);
        stageS[pos] = sreg[it];
    }
    __syncthreads();
    for (int idx = t; idx < 4096; idx += 256) {
        int lo = 0, hi = 255;
        while (lo < hi) { int mid = (lo + hi) >> 1; if (bscan[mid] > idx) hi = mid; else lo = mid + 1; }
        int b = lo;
        int g = gbase[b] + (idx - (bscan[b] - bcnt[b]));
        bpack[g] = stageP[idx];
        bsrc[g] = stageS[idx];
    }
}

// ---------- local sort within bucket ----------
__global__ __launch_bounds__(256) void k_sortb(const u32* __restrict__ bpack, const int* __restrict__ bsrc,
                                               const int* __restrict__ row_ptr,
                                               int* __restrict__ eord, int* __restrict__ ssrc) {
    __shared__ int cur[256];
    int t = threadIdx.x, b = blockIdx.x;
    int nbase = b * 256;
    cur[t] = row_ptr[nbase + t];
    __syncthreads();
    int beg = row_ptr[nbase];
    int end = row_ptr[nbase + 256];
    for (int i = beg + t; i < end; i += 256) {
        u32 wd = bpack[i];
        int src = bsrc[i];
        int d8 = wd & 255;
        int pos = atomicAdd(&cur[d8], 1);
        eord[pos] = (int)(wd >> 12);
        ssrc[pos] = src;
    }
}

// ---------- payload in pos order ----------
__global__ __launch_bounds__(256) void k_payload(const int* __restrict__ eord, const float* __restrict__ ea,
                                                 const float* __restrict__ M1, const float* __restrict__ M2,
                                                 float* __restrict__ a1es, float* __restrict__ a2es) {
    int pos = blockIdx.x * 256 + threadIdx.x;
    int e = eord[pos];
    float v[5];
    for (int j = 0; j < 5; j++) v[j] = ea[(size_t)e * 5 + j];
    float4 o;
    o.x = v[0]*M1[0]  + v[1]*M1[4]  + v[2]*M1[8]  + v[3]*M1[12] + v[4]*M1[16];
    o.y = v[0]*M1[1]  + v[1]*M1[5]  + v[2]*M1[9]  + v[3]*M1[13] + v[4]*M1[17];
    o.z = v[0]*M1[2]  + v[1]*M1[6]  + v[2]*M1[10] + v[3]*M1[14] + v[4]*M1[18];
    o.w = v[0]*M1[3]  + v[1]*M1[7]  + v[2]*M1[11] + v[3]*M1[15] + v[4]*M1[19];
    *(float4*)(a1es + (size_t)pos * 4) = o;
    a2es[pos] = v[0]*M2[0] + v[1]*M2[1] + v[2]*M2[2] + v[3]*M2[3] + v[4]*M2[4];
}

// ---------- register-blocked GEMM: vis = relu(roi @ roiW + b) ----------
__global__ __launch_bounds__(256) void k_vis(const float* __restrict__ A, const float* __restrict__ W,
                                             const float* __restrict__ bias, float* __restrict__ out) {
    __shared__ float At[64][68];
    __shared__ float Wl[64][68];
    int t = threadIdx.x;
    int n0 = blockIdx.x * 64;
    int cg = t & 15, rg = t >> 4;
    int sr = t >> 2, scs = (t & 3) * 16;
    float acc[4][4];
    for (int i = 0; i < 4; i++) for (int j = 0; j < 4; j++) acc[i][j] = 0.f;
    for (int kc = 0; kc < 4; kc++) {
        __syncthreads();
        const float* ap = A + (size_t)(n0 + sr) * 256 + kc * 64 + scs;
        float4 q0 = *(const float4*)ap, q1 = *(const float4*)(ap + 4);
        float4 q2 = *(const float4*)(ap + 8), q3 = *(const float4*)(ap + 12);
        At[scs + 0][sr] = q0.x;  At[scs + 1][sr] = q0.y;  At[scs + 2][sr] = q0.z;  At[scs + 3][sr] = q0.w;
        At[scs + 4][sr] = q1.x;  At[scs + 5][sr] = q1.y;  At[scs + 6][sr] = q1.z;  At[scs + 7][sr] = q1.w;
        At[scs + 8][sr] = q2.x;  At[scs + 9][sr] = q2.y;  At[scs + 10][sr] = q2.z; At[scs + 11][sr] = q2.w;
        At[scs + 12][sr] = q3.x; At[scs + 13][sr] = q3.y; At[scs + 14][sr] = q3.z; At[scs + 15][sr] = q3.w;
        const float* wp = W + (size_t)(kc * 64 + sr) * 64 + scs;
        *(float4*)&Wl[sr][scs + 0]  = *(const float4*)wp;
        *(float4*)&Wl[sr][scs + 4]  = *(const float4*)(wp + 4);
        *(float4*)&Wl[sr][scs + 8]  = *(const float4*)(wp + 8);
        *(float4*)&Wl[sr][scs + 12] = *(const float4*)(wp + 12);
        __syncthreads();
        for (int k = 0; k < 64; k++) {
            float4 a4 = *(const float4*)&At[k][rg * 4];
            float4 w4 = *(const float4*)&Wl[k][cg * 4];
            acc[0][0] += a4.x * w4.x; acc[0][1] += a4.x * w4.y; acc[0][2] += a4.x * w4.z; acc[0][3] += a4.x * w4.w;
            acc[1][0] += a4.y * w4.x; acc[1][1] += a4.y * w4.y; acc[1][2] += a4.y * w4.z; acc[1][3] += a4.y * w4.w;
            acc[2][0] += a4.z * w4.x; acc[2][1] += a4.z * w4.y; acc[2][2] += a4.z * w4.z; acc[2][3] += a4.z * w4.w;
            acc[3][0] += a4.w * w4.x; acc[3][1] += a4.w * w4.y; acc[3][2] += a4.w * w4.z; acc[3][3] += a4.w * w4.w;
        }
    }
    float4 bb = *(const float4*)(bias + cg * 4);
    for (int i = 0; i < 4; i++) {
        float4 o;
        o.x = fmaxf(acc[i][0] + bb.x, 0.f);
        o.y = fmaxf(acc[i][1] + bb.y, 0.f);
        o.z = fmaxf(acc[i][2] + bb.z, 0.f);
        o.w = fmaxf(acc[i][3] + bb.w, 0.f);
        *(float4*)(out + (size_t)(n0 + rg * 4 + i) * 64 + cg * 4) = o;
    }
}

// ---------- register-blocked GEMM: h2 = out1(bf16) @ g2W -> bf16 ----------
__global__ __launch_bounds__(256) void k_h2(const u16* __restrict__ A, const float* __restrict__ W,
                                            u16* __restrict__ out) {
    __shared__ float At[64][68];
    __shared__ float Wl[64][68];
    int t = threadIdx.x;
    int n0 = blockIdx.x * 64;
    int cg = t & 15, rg = t >> 4;
    int sr = t >> 2, scs = (t & 3) * 16;
    float acc[4][4];
    for (int i = 0; i < 4; i++) for (int j = 0; j < 4; j++) acc[i][j] = 0.f;
    for (int kc = 0; kc < 4; kc++) {
        __syncthreads();
        const u16* ap = A + (size_t)(n0 + sr) * 256 + kc * 64 + scs;
        uint4 u0 = *(const uint4*)ap;
        uint4 u1 = *(const uint4*)(ap + 8);
        At[scs + 0][sr] = lo16(u0.x);  At[scs + 1][sr] = hi16(u0.x);
        At[scs + 2][sr] = lo16(u0.y);  At[scs + 3][sr] = hi16(u0.y);
        At[scs + 4][sr] = lo16(u0.z);  At[scs + 5][sr] = hi16(u0.z);
        At[scs + 6][sr] = lo16(u0.w);  At[scs + 7][sr] = hi16(u0.w);
        At[scs + 8][sr] = lo16(u1.x);  At[scs + 9][sr] = hi16(u1.x);
        At[scs + 10][sr] = lo16(u1.y); At[scs + 11][sr] = hi16(u1.y);
        At[scs + 12][sr] = lo16(u1.z); At[scs + 13][sr] = hi16(u1.z);
        At[scs + 14][sr] = lo16(u1.w); At[scs + 15][sr] = hi16(u1.w);
        const float* wp = W + (size_t)(kc * 64 + sr) * 64 + scs;
        *(float4*)&Wl[sr][scs + 0]  = *(const float4*)wp;
        *(float4*)&Wl[sr][scs + 4]  = *(const float4*)(wp + 4);
        *(float4*)&Wl[sr][scs + 8]  = *(const float4*)(wp + 8);
        *(float4*)&Wl[sr][scs + 12] = *(const float4*)(wp + 12);
        __syncthreads();
        for (int k = 0; k < 64; k++) {
            float4 a4 = *(const float4*)&At[k][rg * 4];
            float4 w4 = *(const float4*)&Wl[k][cg * 4];
            acc[0][0] += a4.x * w4.x; acc[0][1] += a4.x * w4.y; acc[0][2] += a4.x * w4.z; acc[0][3] += a4.x * w4.w;
            acc[1][0] += a4.y * w4.x; acc[1][1] += a4.y * w4.y; acc[1][2] += a4.y * w4.z; acc[1][3] += a4.y * w4.w;
            acc[2][0] += a4.z * w4.x; acc[2][1] += a4.z * w4.y; acc[2][2] += a4.z * w4.z; acc[2][3] += a4.z * w4.w;
            acc[3][0] += a4.w * w4.x; acc[3][1] += a4.w * w4.y; acc[3][2] += a4.w * w4.z; acc[3][3] += a4.w * w4.w;
        }
    }
    u32* outu = (u32*)out;
    for (int i = 0; i < 4; i++) {
        uint2 pk;
        pk.x = (u32)f2bf(acc[i][0]) | ((u32)f2bf(acc[i][1]) << 16);
        pk.y = (u32)f2bf(acc[i][2]) | ((u32)f2bf(acc[i][3]) << 16);
        *(uint2*)(outu + (size_t)(n0 + rg * 4 + i) * 32 + cg * 2) = pk;
    }
}

// ---------- h1 = [x | vis] @ g1_W ----------
__global__ __launch_bounds__(256) void k_h1(const float* __restrict__ x, const float* __restrict__ vis,
                                            const float* __restrict__ g1W, u16* __restrict__ h1) {
    __shared__ float At[77][36];
    __shared__ float Wl[77][132];
    int t = threadIdx.x, ch = blockIdx.y;
    int n0 = blockIdx.x * 32;
    int cg = t & 31, rg = t >> 5;
    for (int idx = t; idx < 9856; idx += 256) {
        int k = idx >> 7, c = idx & 127;
        Wl[k][c] = g1W[(size_t)k * 256 + ch * 128 + c];
    }
    for (int idx = t; idx < 2464; idx += 256) {
        int r = idx / 77, k = idx - r * 77;
        At[k][r] = (k < 13) ? x[(size_t)(n0 + r) * 13 + k] : vis[(size_t)(n0 + r) * 64 + (k - 13)];
    }
    __syncthreads();
    float acc[4][4];
    for (int i = 0; i < 4; i++) for (int j = 0; j < 4; j++) acc[i][j] = 0.f;
    for (int k = 0; k < 77; k++) {
        float4 a4 = *(const float4*)&At[k][rg * 4];
        float4 w4 = *(const float4*)&Wl[k][cg * 4];
        acc[0][0] += a4.x * w4.x; acc[0][1] += a4.x * w4.y; acc[0][2] += a4.x * w4.z; acc[0][3] += a4.x * w4.w;
        acc[1][0] += a4.y * w4.x; acc[1][1] += a4.y * w4.y; acc[1][2] += a4.y * w4.z; acc[1][3] += a4.y * w4.w;
        acc[2][0] += a4.z * w4.x; acc[2][1] += a4.z * w4.y; acc[2][2] += a4.z * w4.z; acc[2][3] += a4.z * w4.w;
        acc[3][0] += a4.w * w4.x; acc[3][1] += a4.w * w4.y; acc[3][2] += a4.w * w4.z; acc[3][3] += a4.w * w4.w;
    }
    for (int i = 0; i < 4; i++) {
        uint2 pk;
        pk.x = (u32)f2bf(acc[i][0]) | ((u32)f2bf(acc[i][1]) << 16);
        pk.y = (u32)f2bf(acc[i][2]) | ((u32)f2bf(acc[i][3]) << 16);
        *(uint2*)(h1 + (size_t)(n0 + rg * 4 + i) * 256 + ch * 128 + cg * 4) = pk;
    }
}

// ---------- a1_s/a1_d ----------
__global__ __launch_bounds__(256) void k_a1(const u16* __restrict__ h1, const float* __restrict__ as_,
                                            const float* __restrict__ ad_, float* a1s, float* a1d) {
    int t = threadIdx.x;
    int w = t >> 6, L = t & 63;
    float4 as4 = *(const float4*)(as_ + 4 * L);
    float4 ad4 = *(const float4*)(ad_ + 4 * L);
    int base = (blockIdx.x * 4 + w) * 16;
    for (int j = 0; j < 16; j++) {
        int n = base + j;
        uint2 u = *((const uint2*)(h1 + (size_t)n * 256) + L);
        float v0 = lo16(u.x), v1 = hi16(u.x), v2 = lo16(u.y), v3 = hi16(u.y);
        float ps = v0 * as4.x + v1 * as4.y + v2 * as4.z + v3 * as4.w;
        float pd = v0 * ad4.x + v1 * ad4.y + v2 * ad4.z + v3 * ad4.w;
        for (int o = 1; o < 16; o <<= 1) { ps += __shfl_xor(ps, o, 64); pd += __shfl_xor(pd, o, 64); }
        if ((L & 15) == 0) {
            a1s[n * 4 + (L >> 4)] = ps;
            a1d[n * 4 + (L >> 4)] = pd;
        }
    }
}

__global__ __launch_bounds__(256) void k_a2(const u16* __restrict__ h2b, const float* __restrict__ as_,
                                            const float* __restrict__ ad_, float* a2s, float* a2d) {
    int t = threadIdx.x;
    int w = t >> 6, lane = t & 63;
    int n = blockIdx.x * 4 + w;
    float v = bf2f(h2b[(size_t)n * 64 + lane]);
    float ps = wsum(v * as_[lane]);
    float pd = wsum(v * ad_[lane]);
    if (lane == 0) { a2s[n] = ps; a2d[n] = pd; }
}

// ---------- GAT1 softmax ----------
__global__ __launch_bounds__(256) void k_soft1(const int* __restrict__ row_ptr, const int* __restrict__ ssrc,
                                               const float* __restrict__ a1s, const float* __restrict__ a1d,
                                               const float* __restrict__ a1es, float* __restrict__ w1) {
    int t = threadIdx.x;
    int wv = t >> 6, L = t & 63;
    int n = blockIdx.x * 4 + wv;
    int h = L >> 4, j = L & 15;
    int beg = row_ptr[n], deg = row_ptr[n + 1] - beg;
    if (deg == 0) return;
    float adn = a1d[n * 4 + h];
    float m = -3.0e38f, s = 0.f;
    for (int i = j; i < deg; i += 16) {
        int pos = beg + i;
        float l = a1s[ssrc[pos] * 4 + h] + adn + a1es[(size_t)pos * 4 + h];
        l = (l > 0.f) ? l : 0.2f * l;
        if (l > m) { s = s * __expf(m - l) + 1.f; m = l; }
        else       { s += __expf(l - m); }
    }
    for (int o = 1; o < 16; o <<= 1) {
        float mo = __shfl_xor(m, o, 64), so = __shfl_xor(s, o, 64);
        float M = fmaxf(m, mo);
        s = s * __expf(m - M) + so * __expf(mo - M);
        m = M;
    }
    float inv = 1.f / (s + 1e-16f);
    for (int i = j; i < deg; i += 16) {
        int pos = beg + i;
        float l = a1s[ssrc[pos] * 4 + h] + adn + a1es[(size_t)pos * 4 + h];
        l = (l > 0.f) ? l : 0.2f * l;
        w1[(size_t)pos * 4 + h] = __expf(l - m) * inv;
    }
}

// ---------- GAT1 gather: 2 edges per wave-instruction, uint4 row loads ----------
__global__ __launch_bounds__(256) void k_gath1(const int* __restrict__ row_ptr, const int* __restrict__ ssrc,
                                               const float* __restrict__ w1, const u16* __restrict__ h1,
                                               const float* __restrict__ bias, u16* __restrict__ out1) {
    int t = threadIdx.x;
    int wv = t >> 6, L = t & 63;
    int n = blockIdx.x * 4 + wv;
    int beg = row_ptr[n], deg = row_ptr[n + 1] - beg;
    int halfE = L >> 5;          // which edge of the pair this half-wave handles
    int L32 = L & 31;            // 8 channels: [8*L32, 8*L32+8)
    int hd = L32 >> 3;           // head of those channels
    float acc[8];
    #pragma unroll
    for (int j = 0; j < 8; j++) acc[j] = 0.f;
    int last = beg + deg - 1;
    for (int i = 0; i < deg; i += 4) {
        int iA = i + halfE, iB = i + 2 + halfE;
        int pA = beg + iA, pB = beg + iB;
        bool vA = iA < deg, vB = iB < deg;
        int cA = vA ? pA : last, cB = vB ? pB : last;
        int sA = ssrc[cA], sB = ssrc[cB];
        float wA = vA ? w1[(size_t)cA * 4 + hd] : 0.f;
        float wB = vB ? w1[(size_t)cB * 4 + hd] : 0.f;
        uint4 uA = *((const uint4*)(h1 + (size_t)sA * 256) + L32);
        uint4 uB = *((const uint4*)(h1 + (size_t)sB * 256) + L32);
        acc[0] += wA * lo16(uA.x) + wB * lo16(uB.x);
        acc[1] += wA * hi16(uA.x) + wB * hi16(uB.x);
        acc[2] += wA * lo16(uA.y) + wB * lo16(uB.y);
        acc[3] += wA * hi16(uA.y) + wB * hi16(uB.y);
        acc[4] += wA * lo16(uA.z) + wB * lo16(uB.z);
        acc[5] += wA * hi16(uA.z) + wB * hi16(uB.z);
        acc[6] += wA * lo16(uA.w) + wB * lo16(uB.w);
        acc[7] += wA * hi16(uA.w) + wB * hi16(uB.w);
    }
    // combine edge-parity halves
    #pragma unroll
    for (int j = 0; j < 8; j++) acc[j] += __shfl_xor(acc[j], 32, 64);
    if (halfE == 0) {
        float4 b0 = *(const float4*)(bias + 8 * L32);
        float4 b1 = *(const float4*)(bias + 8 * L32 + 4);
        uint4 pk;
        pk.x = (u32)f2bf(fmaxf(acc[0] + b0.x, 0.f)) | ((u32)f2bf(fmaxf(acc[1] + b0.y, 0.f)) << 16);
        pk.y = (u32)f2bf(fmaxf(acc[2] + b0.z, 0.f)) | ((u32)f2bf(fmaxf(acc[3] + b0.w, 0.f)) << 16);
        pk.z = (u32)f2bf(fmaxf(acc[4] + b1.x, 0.f)) | ((u32)f2bf(fmaxf(acc[5] + b1.y, 0.f)) << 16);
        pk.w = (u32)f2bf(fmaxf(acc[6] + b1.z, 0.f)) | ((u32)f2bf(fmaxf(acc[7] + b1.w, 0.f)) << 16);
        *((uint4*)(out1 + (size_t)n * 256) + L32) = pk;
    }
}

// ---------- GAT2 softmax ----------
__global__ __launch_bounds__(256) void k_soft2(const int* __restrict__ row_ptr, const int* __restrict__ ssrc,
                                               const float* __restrict__ a2s, const float* __restrict__ a2d,
                                               const float* __restrict__ a2es, float* __restrict__ w2) {
    int t = threadIdx.x;
    int wv = t >> 6, L = t & 63;
    int g = L >> 4, j = L & 15;
    int n = blockIdx.x * 16 + wv * 4 + g;
    int beg = row_ptr[n], deg = row_ptr[n + 1] - beg;
    if (deg == 0) return;
    float adn = a2d[n];
    float m = -3.0e38f, s = 0.f;
    for (int i = j; i < deg; i += 16) {
        int pos = beg + i;
        float l = a2s[ssrc[pos]] + adn + a2es[pos];
        l = (l > 0.f) ? l : 0.2f * l;
        if (l > m) { s = s * __expf(m - l) + 1.f; m = l; }
        else       { s += __expf(l - m); }
    }
    for (int o = 1; o < 16; o <<= 1) {
        float mo = __shfl_xor(m, o, 64), so = __shfl_xor(s, o, 64);
        float M = fmaxf(m, mo);
        s = s * __expf(m - M) + so * __expf(mo - M);
        m = M;
    }
    float inv = 1.f / (s + 1e-16f);
    for (int i = j; i < deg; i += 16) {
        int pos = beg + i;
        float l = a2s[ssrc[pos]] + adn + a2es[pos];
        l = (l > 0.f) ? l : 0.2f * l;
        w2[pos] = __expf(l - m) * inv;
    }
}

// ---------- GAT2 gather: 2 edges per wave-instruction, u32 row loads (bf16 rows) ----------
__global__ __launch_bounds__(256) void k_gath2(const int* __restrict__ row_ptr, const int* __restrict__ ssrc,
                                               const float* __restrict__ w2, const u16* __restrict__ h2b,
                                               const float* __restrict__ bias, float* __restrict__ hfin) {
    int t = threadIdx.x;
    int wv = t >> 6, L = t & 63;
    int n = blockIdx.x * 4 + wv;
    int beg = row_ptr[n], deg = row_ptr[n + 1] - beg;
    int halfE = L >> 5;
    int L32 = L & 31;            // 2 channels: 2*L32, 2*L32+1
    float a0 = 0.f, a1v = 0.f;
    int last = beg + deg - 1;
    const u32* h2u = (const u32*)h2b;
    for (int i = 0; i < deg; i += 4) {
        int iA = i + halfE, iB = i + 2 + halfE;
        int pA = beg + iA, pB = beg + iB;
        bool vA = iA < deg, vB = iB < deg;
        int cA = vA ? pA : last, cB = vB ? pB : last;
        int sA = ssrc[cA], sB = ssrc[cB];
        float wA = vA ? w2[cA] : 0.f;
        float wB = vB ? w2[cB] : 0.f;
        u32 uA = h2u[(size_t)sA * 32 + L32];
        u32 uB = h2u[(size_t)sB * 32 + L32];
        a0  += wA * lo16(uA) + wB * lo16(uB);
        a1v += wA * hi16(uA) + wB * hi16(uB);
    }
    a0  += __shfl_xor(a0, 32, 64);
    a1v += __shfl_xor(a1v, 32, 64);
    if (halfE == 0) {
        float2 o;
        o.x = a0  + bias[2 * L32];
        o.y = a1v + bias[2 * L32 + 1];
        *(float2*)(hfin + (size_t)n * 64 + 2 * L32) = o;
    }
}

// ---------- pooling + classifier ----------
__global__ __launch_bounds__(64) void k_pool(const int* __restrict__ bvec, const float* __restrict__ hf,
                                             const float* gateW, const float* gateb,
                                             const float* __restrict__ scene,
                                             const float* c1W, const float* c1b,
                                             const float* c2W, const float* c2b,
                                             float* __restrict__ outp) {
    int b = blockIdx.x, lane = threadIdx.x;
    __shared__ float gwl[64], se[64], comb[192], hid[64];
    gwl[lane] = gateW[lane];
    __syncthreads();
    int s0, s1;
    { int lo = 0, hi = N_NODES; while (lo < hi) { int mid = (lo + hi) >> 1; if (bvec[mid] < b) lo = mid + 1; else hi = mid; } s0 = lo; }
    { int lo = 0, hi = N_NODES; while (lo < hi) { int mid = (lo + hi) >> 1; if (bvec[mid] < b + 1) lo = mid + 1; else hi = mid; } s1 = lo; }
    float gb = gateb[0];
    float m = -3.0e38f, ssum = 0.f, acc = 0.f;
    for (int cs = s0; cs < s1; cs += 64) {
        int cnt = min(64, s1 - cs);
        float l = -3.0e38f;
        if (lane < cnt) {
            int n = cs + lane;
            float d = 0.f;
            for (int i = 0; i < 64; i++) d += hf[(size_t)n * 64 + i] * gwl[i];
            l = d + gb;
        }
        float cm = wmax(l);
        float newm = fmaxf(m, cm);
        float rsc = __expf(m - newm);
        float e = (lane < cnt) ? __expf(l - newm) : 0.f;
        float es = wsum(e);
        ssum = ssum * rsc + es;
        se[lane] = e;
        __syncthreads();
        float a2 = 0.f;
        for (int i = 0; i < cnt; i++) a2 += se[i] * hf[(size_t)(cs + i) * 64 + lane];
        acc = acc * rsc + a2;
        __syncthreads();
        m = newm;
    }
    float rel = acc / (ssum + 1e-16f);
    comb[lane] = scene[b * 128 + lane];
    comb[64 + lane] = scene[b * 128 + 64 + lane];
    comb[128 + lane] = rel;
    __syncthreads();
    float hj = 0.f;
    for (int k = 0; k < 192; k++) hj += comb[k] * c1W[k * 64 + lane];
    hj += c1b[lane];
    hid[lane] = fmaxf(hj, 0.f);
    __syncthreads();
    if (lane < 3) {
        float o = 0.f;
        for (int k = 0; k < 64; k++) o += hid[k] * c2W[k * 3 + lane];
        o += c2b[lane];
        outp[b * 3 + lane] = o;
    }
}

extern "C" void kernel_launch(void* const* d_in, const int* in_sizes, int n_in,
                              void* d_out, int out_size, void* d_ws, size_t ws_size,
                              hipStream_t stream) {
    (void)in_sizes; (void)n_in; (void)out_size; (void)ws_size;
    const float* gf     = (const float*)d_in[0];
    const float* x      = (const float*)d_in[1];
    const float* roi    = (const float*)d_in[2];
    const int*   ei     = (const int*)d_in[3];
    const float* ea     = (const float*)d_in[4];
    const int*   bvec   = (const int*)d_in[5];
    const float* roiW   = (const float*)d_in[6];
    const float* roib   = (const float*)d_in[7];
    const float* sceneW = (const float*)d_in[8];
    const float* sceneb = (const float*)d_in[9];
    const float* g1W    = (const float*)d_in[10];
    const float* g1as   = (const float*)d_in[11];
    const float* g1ad   = (const float*)d_in[12];
    const float* g1We   = (const float*)d_in[13];
    const float* g1ae   = (const float*)d_in[14];
    const float* g1b    = (const float*)d_in[15];
    const float* g2W    = (const float*)d_in[16];
    const float* g2as   = (const float*)d_in[17];
    const float* g2ad   = (const float*)d_in[18];
    const float* g2We   = (const float*)d_in[19];
    const float* g2ae   = (const float*)d_in[20];
    const float* g2b    = (const float*)d_in[21];
    const float* gateW  = (const float*)d_in[22];
    const float* gateb  = (const float*)d_in[23];
    const float* c1W    = (const float*)d_in[24];
    const float* c1b    = (const float*)d_in[25];
    const float* c2W    = (const float*)d_in[26];
    const float* c2b    = (const float*)d_in[27];

    char* w = (char*)d_ws;
    size_t o = 0;
    auto nxt = [&](size_t bytes) -> char* {
        char* p = w + o;
        o += (bytes + 255) & ~(size_t)255;
        return p;
    };
    float* scene  = (float*)nxt((size_t)NB * 128 * 4);
    float* M1     = (float*)nxt(80);
    float* M2     = (float*)nxt(32);
    int* cnt      = (int*)nxt((size_t)N_NODES * 4);
    int* pre      = (int*)nxt((size_t)N_NODES * 4);
    int* bsum     = (int*)nxt(64 * 4);
    int* row_ptr  = (int*)nxt((size_t)(N_NODES + 1) * 4);
    int* coarse   = (int*)nxt(256 * 4);
    u32* bpack    = (u32*)nxt((size_t)N_EDGES * 4);
    int* bsrc     = (int*)nxt((size_t)N_EDGES * 4);
    int* eord     = (int*)nxt((size_t)N_EDGES * 4);
    int* ssrc     = (int*)nxt((size_t)N_EDGES * 4);
    float* a1es   = (float*)nxt((size_t)N_EDGES * 16);
    float* a2es   = (float*)nxt((size_t)N_EDGES * 4);
    float* visbuf = (float*)nxt((size_t)N_NODES * 64 * 4);   // vis, later aliased as w2
    u16* h1       = (u16*)nxt((size_t)N_NODES * 256 * 2);
    u16* out1     = (u16*)nxt((size_t)N_NODES * 256 * 2);
    float* w1buf  = (float*)nxt((size_t)N_EDGES * 16);       // w1, later aliased as h2(bf16)
    float* hfin   = (float*)nxt((size_t)N_NODES * 64 * 4);
    float* a1s    = (float*)nxt((size_t)N_NODES * 16);
    float* a1d    = (float*)nxt((size_t)N_NODES * 16);
    float* a2s    = (float*)nxt((size_t)N_NODES * 4);
    float* a2d    = (float*)nxt((size_t)N_NODES * 4);

    float* vis = visbuf;
    float* w2  = visbuf;      // vis dead after k_h1; w2 written by k_soft2 (later)
    float* w1  = w1buf;
    u16*   h2b = (u16*)w1buf; // w1 dead after k_gath1; h2(bf16) written by k_h2 (later)

    hipMemsetAsync(cnt, 0, (size_t)N_NODES * 4, stream);
    k_prep<<<1, 32, 0, stream>>>(g1We, g1ae, g2We, g2ae, M1, M2);
    k_scene<<<(NB * 128) / 256, 256, 0, stream>>>(gf, sceneW, sceneb, scene);
    k_hist<<<N_EDGES / 256, 256, 0, stream>>>(ei, cnt);
    k_scan_blk<<<64, 256, 0, stream>>>(cnt, pre, bsum);
    k_scan_top<<<1, 64, 0, stream>>>(bsum);
    k_scan_fix<<<N_NODES / 256, 256, 0, stream>>>(pre, bsum, row_ptr, coarse);
    k_bucket<<<256, 256, 0, stream>>>(ei, coarse, bpack, bsrc);
    k_sortb<<<256, 256, 0, stream>>>(bpack, bsrc, row_ptr, eord, ssrc);
    k_payload<<<N_EDGES / 256, 256, 0, stream>>>(eord, ea, M1, M2, a1es, a2es);
    k_vis<<<N_NODES / 64, 256, 0, stream>>>(roi, roiW, roib, vis);
    k_h1<<<dim3(N_NODES / 32, 2), 256, 0, stream>>>(x, vis, g1W, h1);
    k_a1<<<N_NODES / 64, 256, 0, stream>>>(h1, g1as, g1ad, a1s, a1d);
    k_soft1<<<N_NODES / 4, 256, 0, stream>>>(row_ptr, ssrc, a1s, a1d, a1es, w1);
    k_gath1<<<N_NODES / 4, 256, 0, stream>>>(row_ptr, ssrc, w1, h1, g1b, out1);
    k_h2<<<N_NODES / 64, 256, 0, stream>>>(out1, g2W, h2b);
    k_a2<<<N_NODES / 4, 256, 0, stream>>>(h2b, g2as, g2ad, a2s, a2d);
    k_soft2<<<N_NODES / 16, 256, 0, stream>>>(row_ptr, ssrc, a2s, a2d, a2es, w2);
    k_gath2<<<N_NODES / 4, 256, 0, stream>>>(row_ptr, ssrc, w2, h2b, g2b, hfin);
    k_pool<<<NB, 64, 0, stream>>>(bvec, hfin, gateW, gateb, scene, c1W, c1b, c2W, c2b, (float*)d_out);
}

// Round 9
// 624.831 us; speedup vs baseline: 1.0528x; 1.0257x over previous
//
#include <hip/hip_runtime.h>

#define N_NODES 65536
#define N_EDGES 1048576
#define NB      512

typedef unsigned short u16;
typedef unsigned int   u32;
typedef unsigned long long u64;

__device__ __forceinline__ float bf2f(u16 u) { return __uint_as_float(((u32)u) << 16); }
__device__ __forceinline__ float lo16(u32 u) { return __uint_as_float(u << 16); }
__device__ __forceinline__ float hi16(u32 u) { return __uint_as_float(u & 0xffff0000u); }
__device__ __forceinline__ u16 f2bf(float f) {
    u32 u = __float_as_uint(f);
    u32 r = (u + 0x7fffu + ((u >> 16) & 1u)) >> 16;
    return (u16)r;
}
__device__ __forceinline__ float wsum(float v) {
    for (int o = 32; o; o >>= 1) v += __shfl_xor(v, o, 64);
    return v;
}
__device__ __forceinline__ float wmax(float v) {
    for (int o = 32; o; o >>= 1) v = fmaxf(v, __shfl_xor(v, o, 64));
    return v;
}

// ---------- tiny precompute ----------
__global__ void k_prep(const float* g1We, const float* g1ae, const float* g2We, const float* g2ae,
                       float* M1, float* M2) {
    int t = threadIdx.x;
    if (t < 20) {
        int j = t >> 2, h = t & 3;
        float s = 0.f;
        for (int c = 0; c < 64; c++) s += g1We[j * 256 + h * 64 + c] * g1ae[h * 64 + c];
        M1[t] = s;
    } else if (t < 25) {
        int j = t - 20;
        float s = 0.f;
        for (int c = 0; c < 64; c++) s += g2We[j * 64 + c] * g2ae[c];
        M2[j] = s;
    }
}

// ---------- scene ----------
__global__ __launch_bounds__(256) void k_scene(const float* __restrict__ gf, const float* __restrict__ W,
                                               const float* __restrict__ bias, float* __restrict__ scene) {
    int idx = blockIdx.x * 256 + threadIdx.x;
    int b = idx >> 7, j = idx & 127;
    float acc = 0.f;
    for (int k = 0; k < 512; k++) acc += gf[b * 512 + k] * W[k * 128 + j];
    scene[idx] = acc + bias[j];
}

// ---------- histogram ----------
__global__ __launch_bounds__(256) void k_hist(const int* ei, int* cnt) {
    int e = blockIdx.x * 256 + threadIdx.x;
    atomicAdd(&cnt[ei[N_EDGES + e]], 1);
}

// ---------- hierarchical exclusive scan ----------
__global__ __launch_bounds__(256) void k_scan_blk(const int* __restrict__ cnt, int* __restrict__ pre,
                                                  int* __restrict__ bsum) {
    __shared__ int sd[256];
    int t = threadIdx.x, b = blockIdx.x;
    int base = b * 1024 + t * 4;
    int4 c = *(const int4*)(cnt + base);
    int s = c.x + c.y + c.z + c.w;
    sd[t] = s;
    __syncthreads();
    for (int off = 1; off < 256; off <<= 1) {
        int v = (t >= off) ? sd[t - off] : 0;
        __syncthreads();
        sd[t] += v;
        __syncthreads();
    }
    int excl = sd[t] - s;
    int4 p;
    p.x = excl;
    p.y = excl + c.x;
    p.z = excl + c.x + c.y;
    p.w = excl + c.x + c.y + c.z;
    *(int4*)(pre + base) = p;
    if (t == 255) bsum[b] = sd[255];
}

__global__ __launch_bounds__(64) void k_scan_top(int* bsum) {
    int t = threadIdx.x;
    int v = bsum[t];
    int inc = v;
    for (int off = 1; off < 64; off <<= 1) {
        int u = __shfl_up(inc, off, 64);
        if (t >= off) inc += u;
    }
    bsum[t] = inc - v;
}

__global__ __launch_bounds__(256) void k_scan_fix(const int* __restrict__ pre, const int* __restrict__ bsum,
                                                  int* __restrict__ row_ptr, int* __restrict__ coarse_cur) {
    int i = blockIdx.x * 256 + threadIdx.x;
    int v = pre[i] + bsum[i >> 10];
    row_ptr[i] = v;
    if ((i & 255) == 0) coarse_cur[i >> 8] = v;
    if (i == 0) row_ptr[N_NODES] = N_EDGES;
}

// ---------- bucket pass ----------
__global__ __launch_bounds__(256) void k_bucket(const int* __restrict__ ei, int* coarse_cur,
                                                u32* __restrict__ bpack, int* __restrict__ bsrc) {
    __shared__ u32 stageP[4096];
    __shared__ int stageS[4096];
    __shared__ int bcnt[256], bscan[256], boff[256], gbase[256];
    int t = threadIdx.x;
    int e0 = blockIdx.x * 4096;
    bcnt[t] = 0;
    __syncthreads();
    int dreg[16], sreg[16];
    for (int it = 0; it < 16; it++) {
        int e = e0 + it * 256 + t;
        int dd = ei[N_EDGES + e];
        dreg[it] = dd;
        sreg[it] = ei[e];
        atomicAdd(&bcnt[dd >> 8], 1);
    }
    __syncthreads();
    int v = bcnt[t];
    bscan[t] = v;
    __syncthreads();
    for (int off = 1; off < 256; off <<= 1) {
        int u = (t >= off) ? bscan[t - off] : 0;
        __syncthreads();
        bscan[t] += u;
        __syncthreads();
    }
    boff[t] = bscan[t] - v;
    gbase[t] = v ? atomicAdd(&coarse_cur[t], v) : 0;
    __syncthreads();
    for (int it = 0; it < 16; it++) {
        int e = e0 + it * 256 + t;
        int b = dreg[it] >> 8;
        int pos = atomicAdd(&boff[b], 1);
        stageP[pos] = ((u32)e << 12) | (u32)(dreg[it] & 255);
        stageS[pos] = sreg[it];
    }
    __syncthreads();
    for (int idx = t; idx < 4096; idx += 256) {
        int lo = 0, hi = 255;
        while (lo < hi) { int mid = (lo + hi) >> 1; if (bscan[mid] > idx) hi = mid; else lo = mid + 1; }
        int b = lo;
        int g = gbase[b] + (idx - (bscan[b] - bcnt[b]));
        bpack[g] = stageP[idx];
        bsrc[g] = stageS[idx];
    }
}

// ---------- local sort within bucket ----------
__global__ __launch_bounds__(256) void k_sortb(const u32* __restrict__ bpack, const int* __restrict__ bsrc,
                                               const int* __restrict__ row_ptr,
                                               int* __restrict__ eord, int* __restrict__ ssrc) {
    __shared__ int cur[256];
    int t = threadIdx.x, b = blockIdx.x;
    int nbase = b * 256;
    cur[t] = row_ptr[nbase + t];
    __syncthreads();
    int beg = row_ptr[nbase];
    int end = row_ptr[nbase + 256];
    for (int i = beg + t; i < end; i += 256) {
        u32 wd = bpack[i];
        int src = bsrc[i];
        int d8 = wd & 255;
        int pos = atomicAdd(&cur[d8], 1);
        eord[pos] = (int)(wd >> 12);
        ssrc[pos] = src;
    }
}

// ---------- payload in pos order ----------
__global__ __launch_bounds__(256) void k_payload(const int* __restrict__ eord, const float* __restrict__ ea,
                                                 const float* __restrict__ M1, const float* __restrict__ M2,
                                                 float* __restrict__ a1es, float* __restrict__ a2es) {
    int pos = blockIdx.x * 256 + threadIdx.x;
    int e = eord[pos];
    float v[5];
    for (int j = 0; j < 5; j++) v[j] = ea[(size_t)e * 5 + j];
    float4 o;
    o.x = v[0]*M1[0]  + v[1]*M1[4]  + v[2]*M1[8]  + v[3]*M1[12] + v[4]*M1[16];
    o.y = v[0]*M1[1]  + v[1]*M1[5]  + v[2]*M1[9]  + v[3]*M1[13] + v[4]*M1[17];
    o.z = v[0]*M1[2]  + v[1]*M1[6]  + v[2]*M1[10] + v[3]*M1[14] + v[4]*M1[18];
    o.w = v[0]*M1[3]  + v[1]*M1[7]  + v[2]*M1[11] + v[3]*M1[15] + v[4]*M1[19];
    *(float4*)(a1es + (size_t)pos * 4) = o;
    a2es[pos] = v[0]*M2[0] + v[1]*M2[1] + v[2]*M2[2] + v[3]*M2[3] + v[4]*M2[4];
}

// ---------- register-blocked GEMM: vis = relu(roi @ roiW + b) ----------
__global__ __launch_bounds__(256) void k_vis(const float* __restrict__ A, const float* __restrict__ W,
                                             const float* __restrict__ bias, float* __restrict__ out) {
    __shared__ float At[64][68];
    __shared__ float Wl[64][68];
    int t = threadIdx.x;
    int n0 = blockIdx.x * 64;
    int cg = t & 15, rg = t >> 4;
    int sr = t >> 2, scs = (t & 3) * 16;
    float acc[4][4];
    for (int i = 0; i < 4; i++) for (int j = 0; j < 4; j++) acc[i][j] = 0.f;
    for (int kc = 0; kc < 4; kc++) {
        __syncthreads();
        const float* ap = A + (size_t)(n0 + sr) * 256 + kc * 64 + scs;
        float4 q0 = *(const float4*)ap, q1 = *(const float4*)(ap + 4);
        float4 q2 = *(const float4*)(ap + 8), q3 = *(const float4*)(ap + 12);
        At[scs + 0][sr] = q0.x;  At[scs + 1][sr] = q0.y;  At[scs + 2][sr] = q0.z;  At[scs + 3][sr] = q0.w;
        At[scs + 4][sr] = q1.x;  At[scs + 5][sr] = q1.y;  At[scs + 6][sr] = q1.z;  At[scs + 7][sr] = q1.w;
        At[scs + 8][sr] = q2.x;  At[scs + 9][sr] = q2.y;  At[scs + 10][sr] = q2.z; At[scs + 11][sr] = q2.w;
        At[scs + 12][sr] = q3.x; At[scs + 13][sr] = q3.y; At[scs + 14][sr] = q3.z; At[scs + 15][sr] = q3.w;
        const float* wp = W + (size_t)(kc * 64 + sr) * 64 + scs;
        *(float4*)&Wl[sr][scs + 0]  = *(const float4*)wp;
        *(float4*)&Wl[sr][scs + 4]  = *(const float4*)(wp + 4);
        *(float4*)&Wl[sr][scs + 8]  = *(const float4*)(wp + 8);
        *(float4*)&Wl[sr][scs + 12] = *(const float4*)(wp + 12);
        __syncthreads();
        for (int k = 0; k < 64; k++) {
            float4 a4 = *(const float4*)&At[k][rg * 4];
            float4 w4 = *(const float4*)&Wl[k][cg * 4];
            acc[0][0] += a4.x * w4.x; acc[0][1] += a4.x * w4.y; acc[0][2] += a4.x * w4.z; acc[0][3] += a4.x * w4.w;
            acc[1][0] += a4.y * w4.x; acc[1][1] += a4.y * w4.y; acc[1][2] += a4.y * w4.z; acc[1][3] += a4.y * w4.w;
            acc[2][0] += a4.z * w4.x; acc[2][1] += a4.z * w4.y; acc[2][2] += a4.z * w4.z; acc[2][3] += a4.z * w4.w;
            acc[3][0] += a4.w * w4.x; acc[3][1] += a4.w * w4.y; acc[3][2] += a4.w * w4.z; acc[3][3] += a4.w * w4.w;
        }
    }
    float4 bb = *(const float4*)(bias + cg * 4);
    for (int i = 0; i < 4; i++) {
        float4 o;
        o.x = fmaxf(acc[i][0] + bb.x, 0.f);
        o.y = fmaxf(acc[i][1] + bb.y, 0.f);
        o.z = fmaxf(acc[i][2] + bb.z, 0.f);
        o.w = fmaxf(acc[i][3] + bb.w, 0.f);
        *(float4*)(out + (size_t)(n0 + rg * 4 + i) * 64 + cg * 4) = o;
    }
}

// ---------- GEMM: h2 = out1(bf16) @ g2W -> bf16, fused a2s/a2d ----------
__global__ __launch_bounds__(256) void k_h2(const u16* __restrict__ A, const float* __restrict__ W,
                                            const float* __restrict__ as_, const float* __restrict__ ad_,
                                            u16* __restrict__ out, float* __restrict__ a2s,
                                            float* __restrict__ a2d) {
    __shared__ float At[64][68];
    __shared__ float Wl[64][68];
    int t = threadIdx.x;
    int n0 = blockIdx.x * 64;
    int cg = t & 15, rg = t >> 4;
    int sr = t >> 2, scs = (t & 3) * 16;
    float acc[4][4];
    for (int i = 0; i < 4; i++) for (int j = 0; j < 4; j++) acc[i][j] = 0.f;
    for (int kc = 0; kc < 4; kc++) {
        __syncthreads();
        const u16* ap = A + (size_t)(n0 + sr) * 256 + kc * 64 + scs;
        uint4 u0 = *(const uint4*)ap;
        uint4 u1 = *(const uint4*)(ap + 8);
        At[scs + 0][sr] = lo16(u0.x);  At[scs + 1][sr] = hi16(u0.x);
        At[scs + 2][sr] = lo16(u0.y);  At[scs + 3][sr] = hi16(u0.y);
        At[scs + 4][sr] = lo16(u0.z);  At[scs + 5][sr] = hi16(u0.z);
        At[scs + 6][sr] = lo16(u0.w);  At[scs + 7][sr] = hi16(u0.w);
        At[scs + 8][sr] = lo16(u1.x);  At[scs + 9][sr] = hi16(u1.x);
        At[scs + 10][sr] = lo16(u1.y); At[scs + 11][sr] = hi16(u1.y);
        At[scs + 12][sr] = lo16(u1.z); At[scs + 13][sr] = hi16(u1.z);
        At[scs + 14][sr] = lo16(u1.w); At[scs + 15][sr] = hi16(u1.w);
        const float* wp = W + (size_t)(kc * 64 + sr) * 64 + scs;
        *(float4*)&Wl[sr][scs + 0]  = *(const float4*)wp;
        *(float4*)&Wl[sr][scs + 4]  = *(const float4*)(wp + 4);
        *(float4*)&Wl[sr][scs + 8]  = *(const float4*)(wp + 8);
        *(float4*)&Wl[sr][scs + 12] = *(const float4*)(wp + 12);
        __syncthreads();
        for (int k = 0; k < 64; k++) {
            float4 a4 = *(const float4*)&At[k][rg * 4];
            float4 w4 = *(const float4*)&Wl[k][cg * 4];
            acc[0][0] += a4.x * w4.x; acc[0][1] += a4.x * w4.y; acc[0][2] += a4.x * w4.z; acc[0][3] += a4.x * w4.w;
            acc[1][0] += a4.y * w4.x; acc[1][1] += a4.y * w4.y; acc[1][2] += a4.y * w4.z; acc[1][3] += a4.y * w4.w;
            acc[2][0] += a4.z * w4.x; acc[2][1] += a4.z * w4.y; acc[2][2] += a4.z * w4.z; acc[2][3] += a4.z * w4.w;
            acc[3][0] += a4.w * w4.x; acc[3][1] += a4.w * w4.y; acc[3][2] += a4.w * w4.z; acc[3][3] += a4.w * w4.w;
        }
    }
    u32* outu = (u32*)out;
    for (int i = 0; i < 4; i++) {
        uint2 pk;
        pk.x = (u32)f2bf(acc[i][0]) | ((u32)f2bf(acc[i][1]) << 16);
        pk.y = (u32)f2bf(acc[i][2]) | ((u32)f2bf(acc[i][3]) << 16);
        *(uint2*)(outu + (size_t)(n0 + rg * 4 + i) * 32 + cg * 2) = pk;
    }
    // fused a2s/a2d: 16-lane reduction across cg for each of this thread's 4 rows
    float4 as4 = *(const float4*)(as_ + cg * 4);
    float4 ad4 = *(const float4*)(ad_ + cg * 4);
    #pragma unroll
    for (int i = 0; i < 4; i++) {
        float ps = acc[i][0] * as4.x + acc[i][1] * as4.y + acc[i][2] * as4.z + acc[i][3] * as4.w;
        float pd = acc[i][0] * ad4.x + acc[i][1] * ad4.y + acc[i][2] * ad4.z + acc[i][3] * ad4.w;
        for (int o = 1; o < 16; o <<= 1) { ps += __shfl_xor(ps, o, 64); pd += __shfl_xor(pd, o, 64); }
        if (cg == 0) {
            a2s[n0 + rg * 4 + i] = ps;
            a2d[n0 + rg * 4 + i] = pd;
        }
    }
}

// ---------- h1 = [x | vis] @ g1_W ----------
__global__ __launch_bounds__(256) void k_h1(const float* __restrict__ x, const float* __restrict__ vis,
                                            const float* __restrict__ g1W, u16* __restrict__ h1) {
    __shared__ float At[77][36];
    __shared__ float Wl[77][132];
    int t = threadIdx.x, ch = blockIdx.y;
    int n0 = blockIdx.x * 32;
    int cg = t & 31, rg = t >> 5;
    for (int idx = t; idx < 9856; idx += 256) {
        int k = idx >> 7, c = idx & 127;
        Wl[k][c] = g1W[(size_t)k * 256 + ch * 128 + c];
    }
    for (int idx = t; idx < 2464; idx += 256) {
        int r = idx / 77, k = idx - r * 77;
        At[k][r] = (k < 13) ? x[(size_t)(n0 + r) * 13 + k] : vis[(size_t)(n0 + r) * 64 + (k - 13)];
    }
    __syncthreads();
    float acc[4][4];
    for (int i = 0; i < 4; i++) for (int j = 0; j < 4; j++) acc[i][j] = 0.f;
    for (int k = 0; k < 77; k++) {
        float4 a4 = *(const float4*)&At[k][rg * 4];
        float4 w4 = *(const float4*)&Wl[k][cg * 4];
        acc[0][0] += a4.x * w4.x; acc[0][1] += a4.x * w4.y; acc[0][2] += a4.x * w4.z; acc[0][3] += a4.x * w4.w;
        acc[1][0] += a4.y * w4.x; acc[1][1] += a4.y * w4.y; acc[1][2] += a4.y * w4.z; acc[1][3] += a4.y * w4.w;
        acc[2][0] += a4.z * w4.x; acc[2][1] += a4.z * w4.y; acc[2][2] += a4.z * w4.z; acc[2][3] += a4.z * w4.w;
        acc[3][0] += a4.w * w4.x; acc[3][1] += a4.w * w4.y; acc[3][2] += a4.w * w4.z; acc[3][3] += a4.w * w4.w;
    }
    for (int i = 0; i < 4; i++) {
        uint2 pk;
        pk.x = (u32)f2bf(acc[i][0]) | ((u32)f2bf(acc[i][1]) << 16);
        pk.y = (u32)f2bf(acc[i][2]) | ((u32)f2bf(acc[i][3]) << 16);
        *(uint2*)(h1 + (size_t)(n0 + rg * 4 + i) * 256 + ch * 128 + cg * 4) = pk;
    }
}

// ---------- a1_s/a1_d ----------
__global__ __launch_bounds__(256) void k_a1(const u16* __restrict__ h1, const float* __restrict__ as_,
                                            const float* __restrict__ ad_, float* a1s, float* a1d) {
    int t = threadIdx.x;
    int w = t >> 6, L = t & 63;
    float4 as4 = *(const float4*)(as_ + 4 * L);
    float4 ad4 = *(const float4*)(ad_ + 4 * L);
    int base = (blockIdx.x * 4 + w) * 16;
    for (int j = 0; j < 16; j++) {
        int n = base + j;
        uint2 u = *((const uint2*)(h1 + (size_t)n * 256) + L);
        float v0 = lo16(u.x), v1 = hi16(u.x), v2 = lo16(u.y), v3 = hi16(u.y);
        float ps = v0 * as4.x + v1 * as4.y + v2 * as4.z + v3 * as4.w;
        float pd = v0 * ad4.x + v1 * ad4.y + v2 * ad4.z + v3 * ad4.w;
        for (int o = 1; o < 16; o <<= 1) { ps += __shfl_xor(ps, o, 64); pd += __shfl_xor(pd, o, 64); }
        if ((L & 15) == 0) {
            a1s[n * 4 + (L >> 4)] = ps;
            a1d[n * 4 + (L >> 4)] = pd;
        }
    }
}

// ---------- GAT1 softmax: pass1 caches logits in w1, pass2 normalizes ----------
__global__ __launch_bounds__(256) void k_soft1(const int* __restrict__ row_ptr, const int* __restrict__ ssrc,
                                               const float* __restrict__ a1s, const float* __restrict__ a1d,
                                               const float* __restrict__ a1es, float* __restrict__ w1) {
    int t = threadIdx.x;
    int wv = t >> 6, L = t & 63;
    int n = blockIdx.x * 4 + wv;
    int h = L >> 4, j = L & 15;
    int beg = row_ptr[n], deg = row_ptr[n + 1] - beg;
    if (deg == 0) return;
    float adn = a1d[n * 4 + h];
    float m = -3.0e38f, s = 0.f;
    for (int i = j; i < deg; i += 16) {
        int pos = beg + i;
        float l = a1s[ssrc[pos] * 4 + h] + adn + a1es[(size_t)pos * 4 + h];
        l = (l > 0.f) ? l : 0.2f * l;
        w1[(size_t)pos * 4 + h] = l;
        if (l > m) { s = s * __expf(m - l) + 1.f; m = l; }
        else       { s += __expf(l - m); }
    }
    for (int o = 1; o < 16; o <<= 1) {
        float mo = __shfl_xor(m, o, 64), so = __shfl_xor(s, o, 64);
        float M = fmaxf(m, mo);
        s = s * __expf(m - M) + so * __expf(mo - M);
        m = M;
    }
    float inv = 1.f / (s + 1e-16f);
    for (int i = j; i < deg; i += 16) {
        int pos = beg + i;
        float l = w1[(size_t)pos * 4 + h];
        w1[(size_t)pos * 4 + h] = __expf(l - m) * inv;
    }
}

// ---------- GAT1 gather: 4 edges in flight per lane, uint4 row loads ----------
__global__ __launch_bounds__(256) void k_gath1(const int* __restrict__ row_ptr, const int* __restrict__ ssrc,
                                               const float* __restrict__ w1, const u16* __restrict__ h1,
                                               const float* __restrict__ bias, u16* __restrict__ out1) {
    int t = threadIdx.x;
    int wv = t >> 6, L = t & 63;
    int n = blockIdx.x * 4 + wv;
    int beg = row_ptr[n], deg = row_ptr[n + 1] - beg;
    int halfE = L >> 5;          // edge parity for this half-wave
    int L32 = L & 31;            // 8 channels: [8*L32, 8*L32+8)
    int hd = L32 >> 3;           // head of those channels
    float acc[8];
    #pragma unroll
    for (int j = 0; j < 8; j++) acc[j] = 0.f;
    int last = beg + deg - 1;
    for (int i = 0; i < deg; i += 8) {
        int iA = i + halfE, iB = i + 2 + halfE, iC = i + 4 + halfE, iD = i + 6 + halfE;
        bool vA = iA < deg, vB = iB < deg, vC = iC < deg, vD = iD < deg;
        int cA = vA ? beg + iA : last, cB = vB ? beg + iB : last;
        int cC = vC ? beg + iC : last, cD = vD ? beg + iD : last;
        int sA = ssrc[cA], sB = ssrc[cB], sC = ssrc[cC], sD = ssrc[cD];
        float wA = vA ? w1[(size_t)cA * 4 + hd] : 0.f;
        float wB = vB ? w1[(size_t)cB * 4 + hd] : 0.f;
        float wC = vC ? w1[(size_t)cC * 4 + hd] : 0.f;
        float wD = vD ? w1[(size_t)cD * 4 + hd] : 0.f;
        uint4 uA = *((const uint4*)(h1 + (size_t)sA * 256) + L32);
        uint4 uB = *((const uint4*)(h1 + (size_t)sB * 256) + L32);
        uint4 uC = *((const uint4*)(h1 + (size_t)sC * 256) + L32);
        uint4 uD = *((const uint4*)(h1 + (size_t)sD * 256) + L32);
        acc[0] += wA * lo16(uA.x) + wB * lo16(uB.x) + wC * lo16(uC.x) + wD * lo16(uD.x);
        acc[1] += wA * hi16(uA.x) + wB * hi16(uB.x) + wC * hi16(uC.x) + wD * hi16(uD.x);
        acc[2] += wA * lo16(uA.y) + wB * lo16(uB.y) + wC * lo16(uC.y) + wD * lo16(uD.y);
        acc[3] += wA * hi16(uA.y) + wB * hi16(uB.y) + wC * hi16(uC.y) + wD * hi16(uD.y);
        acc[4] += wA * lo16(uA.z) + wB * lo16(uB.z) + wC * lo16(uC.z) + wD * lo16(uD.z);
        acc[5] += wA * hi16(uA.z) + wB * hi16(uB.z) + wC * hi16(uC.z) + wD * hi16(uD.z);
        acc[6] += wA * lo16(uA.w) + wB * lo16(uB.w) + wC * lo16(uC.w) + wD * lo16(uD.w);
        acc[7] += wA * hi16(uA.w) + wB * hi16(uB.w) + wC * hi16(uC.w) + wD * hi16(uD.w);
    }
    #pragma unroll
    for (int j = 0; j < 8; j++) acc[j] += __shfl_xor(acc[j], 32, 64);
    if (halfE == 0) {
        float4 b0 = *(const float4*)(bias + 8 * L32);
        float4 b1 = *(const float4*)(bias + 8 * L32 + 4);
        uint4 pk;
        pk.x = (u32)f2bf(fmaxf(acc[0] + b0.x, 0.f)) | ((u32)f2bf(fmaxf(acc[1] + b0.y, 0.f)) << 16);
        pk.y = (u32)f2bf(fmaxf(acc[2] + b0.z, 0.f)) | ((u32)f2bf(fmaxf(acc[3] + b0.w, 0.f)) << 16);
        pk.z = (u32)f2bf(fmaxf(acc[4] + b1.x, 0.f)) | ((u32)f2bf(fmaxf(acc[5] + b1.y, 0.f)) << 16);
        pk.w = (u32)f2bf(fmaxf(acc[6] + b1.z, 0.f)) | ((u32)f2bf(fmaxf(acc[7] + b1.w, 0.f)) << 16);
        *((uint4*)(out1 + (size_t)n * 256) + L32) = pk;
    }
}

// ---------- GAT2 softmax ----------
__global__ __launch_bounds__(256) void k_soft2(const int* __restrict__ row_ptr, const int* __restrict__ ssrc,
                                               const float* __restrict__ a2s, const float* __restrict__ a2d,
                                               const float* __restrict__ a2es, float* __restrict__ w2) {
    int t = threadIdx.x;
    int wv = t >> 6, L = t & 63;
    int g = L >> 4, j = L & 15;
    int n = blockIdx.x * 16 + wv * 4 + g;
    int beg = row_ptr[n], deg = row_ptr[n + 1] - beg;
    if (deg == 0) return;
    float adn = a2d[n];
    float m = -3.0e38f, s = 0.f;
    for (int i = j; i < deg; i += 16) {
        int pos = beg + i;
        float l = a2s[ssrc[pos]] + adn + a2es[pos];
        l = (l > 0.f) ? l : 0.2f * l;
        w2[pos] = l;
        if (l > m) { s = s * __expf(m - l) + 1.f; m = l; }
        else       { s += __expf(l - m); }
    }
    for (int o = 1; o < 16; o <<= 1) {
        float mo = __shfl_xor(m, o, 64), so = __shfl_xor(s, o, 64);
        float M = fmaxf(m, mo);
        s = s * __expf(m - M) + so * __expf(mo - M);
        m = M;
    }
    float inv = 1.f / (s + 1e-16f);
    for (int i = j; i < deg; i += 16) {
        int pos = beg + i;
        float l = w2[pos];
        w2[pos] = __expf(l - m) * inv;
    }
}

// ---------- GAT2 gather ----------
__global__ __launch_bounds__(256) void k_gath2(const int* __restrict__ row_ptr, const int* __restrict__ ssrc,
                                               const float* __restrict__ w2, const u16* __restrict__ h2b,
                                               const float* __restrict__ bias, float* __restrict__ hfin) {
    int t = threadIdx.x;
    int wv = t >> 6, L = t & 63;
    int n = blockIdx.x * 4 + wv;
    int beg = row_ptr[n], deg = row_ptr[n + 1] - beg;
    int halfE = L >> 5;
    int L32 = L & 31;
    float a0 = 0.f, a1v = 0.f;
    int last = beg + deg - 1;
    const u32* h2u = (const u32*)h2b;
    for (int i = 0; i < deg; i += 8) {
        int iA = i + halfE, iB = i + 2 + halfE, iC = i + 4 + halfE, iD = i + 6 + halfE;
        bool vA = iA < deg, vB = iB < deg, vC = iC < deg, vD = iD < deg;
        int cA = vA ? beg + iA : last, cB = vB ? beg + iB : last;
        int cC = vC ? beg + iC : last, cD = vD ? beg + iD : last;
        int sA = ssrc[cA], sB = ssrc[cB], sC = ssrc[cC], sD = ssrc[cD];
        float wA = vA ? w2[cA] : 0.f;
        float wB = vB ? w2[cB] : 0.f;
        float wC = vC ? w2[cC] : 0.f;
        float wD = vD ? w2[cD] : 0.f;
        u32 uA = h2u[(size_t)sA * 32 + L32];
        u32 uB = h2u[(size_t)sB * 32 + L32];
        u32 uC = h2u[(size_t)sC * 32 + L32];
        u32 uD = h2u[(size_t)sD * 32 + L32];
        a0  += wA * lo16(uA) + wB * lo16(uB) + wC * lo16(uC) + wD * lo16(uD);
        a1v += wA * hi16(uA) + wB * hi16(uB) + wC * hi16(uC) + wD * hi16(uD);
    }
    a0  += __shfl_xor(a0, 32, 64);
    a1v += __shfl_xor(a1v, 32, 64);
    if (halfE == 0) {
        float2 o;
        o.x = a0  + bias[2 * L32];
        o.y = a1v + bias[2 * L32 + 1];
        *(float2*)(hfin + (size_t)n * 64 + 2 * L32) = o;
    }
}

// ---------- pooling + classifier ----------
__global__ __launch_bounds__(64) void k_pool(const int* __restrict__ bvec, const float* __restrict__ hf,
                                             const float* gateW, const float* gateb,
                                             const float* __restrict__ scene,
                                             const float* c1W, const float* c1b,
                                             const float* c2W, const float* c2b,
                                             float* __restrict__ outp) {
    int b = blockIdx.x, lane = threadIdx.x;
    __shared__ float gwl[64], se[64], comb[192], hid[64];
    gwl[lane] = gateW[lane];
    __syncthreads();
    int s0, s1;
    { int lo = 0, hi = N_NODES; while (lo < hi) { int mid = (lo + hi) >> 1; if (bvec[mid] < b) lo = mid + 1; else hi = mid; } s0 = lo; }
    { int lo = 0, hi = N_NODES; while (lo < hi) { int mid = (lo + hi) >> 1; if (bvec[mid] < b + 1) lo = mid + 1; else hi = mid; } s1 = lo; }
    float gb = gateb[0];
    float m = -3.0e38f, ssum = 0.f, acc = 0.f;
    for (int cs = s0; cs < s1; cs += 64) {
        int cnt = min(64, s1 - cs);
        float l = -3.0e38f;
        if (lane < cnt) {
            int n = cs + lane;
            float d = 0.f;
            for (int i = 0; i < 64; i++) d += hf[(size_t)n * 64 + i] * gwl[i];
            l = d + gb;
        }
        float cm = wmax(l);
        float newm = fmaxf(m, cm);
        float rsc = __expf(m - newm);
        float e = (lane < cnt) ? __expf(l - newm) : 0.f;
        float es = wsum(e);
        ssum = ssum * rsc + es;
        se[lane] = e;
        __syncthreads();
        float a2 = 0.f;
        for (int i = 0; i < cnt; i++) a2 += se[i] * hf[(size_t)(cs + i) * 64 + lane];
        acc = acc * rsc + a2;
        __syncthreads();
        m = newm;
    }
    float rel = acc / (ssum + 1e-16f);
    comb[lane] = scene[b * 128 + lane];
    comb[64 + lane] = scene[b * 128 + 64 + lane];
    comb[128 + lane] = rel;
    __syncthreads();
    float hj = 0.f;
    for (int k = 0; k < 192; k++) hj += comb[k] * c1W[k * 64 + lane];
    hj += c1b[lane];
    hid[lane] = fmaxf(hj, 0.f);
    __syncthreads();
    if (lane < 3) {
        float o = 0.f;
        for (int k = 0; k < 64; k++) o += hid[k] * c2W[k * 3 + lane];
        o += c2b[lane];
        outp[b * 3 + lane] = o;
    }
}

extern "C" void kernel_launch(void* const* d_in, const int* in_sizes, int n_in,
                              void* d_out, int out_size, void* d_ws, size_t ws_size,
                              hipStream_t stream) {
    (void)in_sizes; (void)n_in; (void)out_size; (void)ws_size;
    const float* gf     = (const float*)d_in[0];
    const float* x      = (const float*)d_in[1];
    const float* roi    = (const float*)d_in[2];
    const int*   ei     = (const int*)d_in[3];
    const float* ea     = (const float*)d_in[4];
    const int*   bvec   = (const int*)d_in[5];
    const float* roiW   = (const float*)d_in[6];
    const float* roib   = (const float*)d_in[7];
    const float* sceneW = (const float*)d_in[8];
    const float* sceneb = (const float*)d_in[9];
    const float* g1W    = (const float*)d_in[10];
    const float* g1as   = (const float*)d_in[11];
    const float* g1ad   = (const float*)d_in[12];
    const float* g1We   = (const float*)d_in[13];
    const float* g1ae   = (const float*)d_in[14];
    const float* g1b    = (const float*)d_in[15];
    const float* g2W    = (const float*)d_in[16];
    const float* g2as   = (const float*)d_in[17];
    const float* g2ad   = (const float*)d_in[18];
    const float* g2We   = (const float*)d_in[19];
    const float* g2ae   = (const float*)d_in[20];
    const float* g2b    = (const float*)d_in[21];
    const float* gateW  = (const float*)d_in[22];
    const float* gateb  = (const float*)d_in[23];
    const float* c1W    = (const float*)d_in[24];
    const float* c1b    = (const float*)d_in[25];
    const float* c2W    = (const float*)d_in[26];
    const float* c2b    = (const float*)d_in[27];

    char* w = (char*)d_ws;
    size_t o = 0;
    auto nxt = [&](size_t bytes) -> char* {
        char* p = w + o;
        o += (bytes + 255) & ~(size_t)255;
        return p;
    };
    float* scene  = (float*)nxt((size_t)NB * 128 * 4);
    float* M1     = (float*)nxt(80);
    float* M2     = (float*)nxt(32);
    int* cnt      = (int*)nxt((size_t)N_NODES * 4);
    int* pre      = (int*)nxt((size_t)N_NODES * 4);
    int* bsum     = (int*)nxt(64 * 4);
    int* row_ptr  = (int*)nxt((size_t)(N_NODES + 1) * 4);
    int* coarse   = (int*)nxt(256 * 4);
    u32* bpack    = (u32*)nxt((size_t)N_EDGES * 4);
    int* bsrc     = (int*)nxt((size_t)N_EDGES * 4);
    int* eord     = (int*)nxt((size_t)N_EDGES * 4);
    int* ssrc     = (int*)nxt((size_t)N_EDGES * 4);
    float* a1es   = (float*)nxt((size_t)N_EDGES * 16);
    float* a2es   = (float*)nxt((size_t)N_EDGES * 4);
    float* visbuf = (float*)nxt((size_t)N_NODES * 64 * 4);   // vis, later aliased as w2
    u16* h1       = (u16*)nxt((size_t)N_NODES * 256 * 2);
    u16* out1     = (u16*)nxt((size_t)N_NODES * 256 * 2);
    float* w1buf  = (float*)nxt((size_t)N_EDGES * 16);       // w1, later aliased as h2(bf16)
    float* hfin   = (float*)nxt((size_t)N_NODES * 64 * 4);
    float* a1s    = (float*)nxt((size_t)N_NODES * 16);
    float* a1d    = (float*)nxt((size_t)N_NODES * 16);
    float* a2s    = (float*)nxt((size_t)N_NODES * 4);
    float* a2d    = (float*)nxt((size_t)N_NODES * 4);

    float* vis = visbuf;
    float* w2  = visbuf;      // vis dead after k_h1; w2 written by k_soft2 (later)
    float* w1  = w1buf;
    u16*   h2b = (u16*)w1buf; // w1 dead after k_gath1; h2(bf16) written by k_h2 (later)

    hipMemsetAsync(cnt, 0, (size_t)N_NODES * 4, stream);
    k_prep<<<1, 32, 0, stream>>>(g1We, g1ae, g2We, g2ae, M1, M2);
    k_scene<<<(NB * 128) / 256, 256, 0, stream>>>(gf, sceneW, sceneb, scene);
    k_hist<<<N_EDGES / 256, 256, 0, stream>>>(ei, cnt);
    k_scan_blk<<<64, 256, 0, stream>>>(cnt, pre, bsum);
    k_scan_top<<<1, 64, 0, stream>>>(bsum);
    k_scan_fix<<<N_NODES / 256, 256, 0, stream>>>(pre, bsum, row_ptr, coarse);
    k_bucket<<<256, 256, 0, stream>>>(ei, coarse, bpack, bsrc);
    k_sortb<<<256, 256, 0, stream>>>(bpack, bsrc, row_ptr, eord, ssrc);
    k_payload<<<N_EDGES / 256, 256, 0, stream>>>(eord, ea, M1, M2, a1es, a2es);
    k_vis<<<N_NODES / 64, 256, 0, stream>>>(roi, roiW, roib, vis);
    k_h1<<<dim3(N_NODES / 32, 2), 256, 0, stream>>>(x, vis, g1W, h1);
    k_a1<<<N_NODES / 64, 256, 0, stream>>>(h1, g1as, g1ad, a1s, a1d);
    k_soft1<<<N_NODES / 4, 256, 0, stream>>>(row_ptr, ssrc, a1s, a1d, a1es, w1);
    k_gath1<<<N_NODES / 4, 256, 0, stream>>>(row_ptr, ssrc, w1, h1, g1b, out1);
    k_h2<<<N_NODES / 64, 256, 0, stream>>>(out1, g2W, g2as, g2ad, h2b, a2s, a2d);
    k_soft2<<<N_NODES / 16, 256, 0, stream>>>(row_ptr, ssrc, a2s, a2d, a2es, w2);
    k_gath2<<<N_NODES / 4, 256, 0, stream>>>(row_ptr, ssrc, w2, h2b, g2b, hfin);
    k_pool<<<NB, 64, 0, stream>>>(bvec, hfin, gateW, gateb, scene, c1W, c1b, c2W, c2b, (float*)d_out);
}

// Round 10
// 611.961 us; speedup vs baseline: 1.0749x; 1.0210x over previous
//
#include <hip/hip_runtime.h>

#define N_NODES 65536
#define N_EDGES 1048576
#define NB      512

typedef unsigned short u16;
typedef unsigned int   u32;
typedef unsigned long long u64;

__device__ __forceinline__ float bf2f(u16 u) { return __uint_as_float(((u32)u) << 16); }
__device__ __forceinline__ float lo16(u32 u) { return __uint_as_float(u << 16); }
__device__ __forceinline__ float hi16(u32 u) { return __uint_as_float(u & 0xffff0000u); }
__device__ __forceinline__ u16 f2bf(float f) {
    u32 u = __float_as_uint(f);
    u32 r = (u + 0x7fffu + ((u >> 16) & 1u)) >> 16;
    return (u16)r;
}
__device__ __forceinline__ float wsum(float v) {
    for (int o = 32; o; o >>= 1) v += __shfl_xor(v, o, 64);
    return v;
}
__device__ __forceinline__ float wmax(float v) {
    for (int o = 32; o; o >>= 1) v = fmaxf(v, __shfl_xor(v, o, 64));
    return v;
}

// ---------- tiny precompute ----------
__global__ void k_prep(const float* g1We, const float* g1ae, const float* g2We, const float* g2ae,
                       float* M1, float* M2) {
    int t = threadIdx.x;
    if (t < 20) {
        int j = t >> 2, h = t & 3;
        float s = 0.f;
        for (int c = 0; c < 64; c++) s += g1We[j * 256 + h * 64 + c] * g1ae[h * 64 + c];
        M1[t] = s;
    } else if (t < 25) {
        int j = t - 20;
        float s = 0.f;
        for (int c = 0; c < 64; c++) s += g2We[j * 64 + c] * g2ae[c];
        M2[j] = s;
    }
}

// ---------- scene ----------
__global__ __launch_bounds__(256) void k_scene(const float* __restrict__ gf, const float* __restrict__ W,
                                               const float* __restrict__ bias, float* __restrict__ scene) {
    int idx = blockIdx.x * 256 + threadIdx.x;
    int b = idx >> 7, j = idx & 127;
    float acc = 0.f;
    for (int k = 0; k < 512; k++) acc += gf[b * 512 + k] * W[k * 128 + j];
    scene[idx] = acc + bias[j];
}

// ---------- histogram ----------
__global__ __launch_bounds__(256) void k_hist(const int* ei, int* cnt) {
    int e = blockIdx.x * 256 + threadIdx.x;
    atomicAdd(&cnt[ei[N_EDGES + e]], 1);
}

// ---------- hierarchical exclusive scan ----------
__global__ __launch_bounds__(256) void k_scan_blk(const int* __restrict__ cnt, int* __restrict__ pre,
                                                  int* __restrict__ bsum) {
    __shared__ int sd[256];
    int t = threadIdx.x, b = blockIdx.x;
    int base = b * 1024 + t * 4;
    int4 c = *(const int4*)(cnt + base);
    int s = c.x + c.y + c.z + c.w;
    sd[t] = s;
    __syncthreads();
    for (int off = 1; off < 256; off <<= 1) {
        int v = (t >= off) ? sd[t - off] : 0;
        __syncthreads();
        sd[t] += v;
        __syncthreads();
    }
    int excl = sd[t] - s;
    int4 p;
    p.x = excl;
    p.y = excl + c.x;
    p.z = excl + c.x + c.y;
    p.w = excl + c.x + c.y + c.z;
    *(int4*)(pre + base) = p;
    if (t == 255) bsum[b] = sd[255];
}

__global__ __launch_bounds__(64) void k_scan_top(int* bsum) {
    int t = threadIdx.x;
    int v = bsum[t];
    int inc = v;
    for (int off = 1; off < 64; off <<= 1) {
        int u = __shfl_up(inc, off, 64);
        if (t >= off) inc += u;
    }
    bsum[t] = inc - v;
}

__global__ __launch_bounds__(256) void k_scan_fix(const int* __restrict__ pre, const int* __restrict__ bsum,
                                                  int* __restrict__ row_ptr, int* __restrict__ coarse_cur) {
    int i = blockIdx.x * 256 + threadIdx.x;
    int v = pre[i] + bsum[i >> 10];
    row_ptr[i] = v;
    if ((i & 255) == 0) coarse_cur[i >> 8] = v;
    if (i == 0) row_ptr[N_NODES] = N_EDGES;
}

// ---------- bucket pass ----------
__global__ __launch_bounds__(256) void k_bucket(const int* __restrict__ ei, int* coarse_cur,
                                                u32* __restrict__ bpack, int* __restrict__ bsrc) {
    __shared__ u32 stageP[4096];
    __shared__ int stageS[4096];
    __shared__ int bcnt[256], bscan[256], boff[256], gbase[256];
    int t = threadIdx.x;
    int e0 = blockIdx.x * 4096;
    bcnt[t] = 0;
    __syncthreads();
    int dreg[16], sreg[16];
    for (int it = 0; it < 16; it++) {
        int e = e0 + it * 256 + t;
        int dd = ei[N_EDGES + e];
        dreg[it] = dd;
        sreg[it] = ei[e];
        atomicAdd(&bcnt[dd >> 8], 1);
    }
    __syncthreads();
    int v = bcnt[t];
    bscan[t] = v;
    __syncthreads();
    for (int off = 1; off < 256; off <<= 1) {
        int u = (t >= off) ? bscan[t - off] : 0;
        __syncthreads();
        bscan[t] += u;
        __syncthreads();
    }
    boff[t] = bscan[t] - v;
    gbase[t] = v ? atomicAdd(&coarse_cur[t], v) : 0;
    __syncthreads();
    for (int it = 0; it < 16; it++) {
        int e = e0 + it * 256 + t;
        int b = dreg[it] >> 8;
        int pos = atomicAdd(&boff[b], 1);
        stageP[pos] = ((u32)e << 12) | (u32)(dreg[it] & 255);
        stageS[pos] = sreg[it];
    }
    __syncthreads();
    for (int idx = t; idx < 4096; idx += 256) {
        int lo = 0, hi = 255;
        while (lo < hi) { int mid = (lo + hi) >> 1; if (bscan[mid] > idx) hi = mid; else lo = mid + 1; }
        int b = lo;
        int g = gbase[b] + (idx - (bscan[b] - bcnt[b]));
        bpack[g] = stageP[idx];
        bsrc[g] = stageS[idx];
    }
}

// ---------- local sort within bucket ----------
__global__ __launch_bounds__(256) void k_sortb(const u32* __restrict__ bpack, const int* __restrict__ bsrc,
                                               const int* __restrict__ row_ptr,
                                               int* __restrict__ eord, int* __restrict__ ssrc) {
    __shared__ int cur[256];
    int t = threadIdx.x, b = blockIdx.x;
    int nbase = b * 256;
    cur[t] = row_ptr[nbase + t];
    __syncthreads();
    int beg = row_ptr[nbase];
    int end = row_ptr[nbase + 256];
    for (int i = beg + t; i < end; i += 256) {
        u32 wd = bpack[i];
        int src = bsrc[i];
        int d8 = wd & 255;
        int pos = atomicAdd(&cur[d8], 1);
        eord[pos] = (int)(wd >> 12);
        ssrc[pos] = src;
    }
}

// ---------- payload in pos order ----------
__global__ __launch_bounds__(256) void k_payload(const int* __restrict__ eord, const float* __restrict__ ea,
                                                 const float* __restrict__ M1, const float* __restrict__ M2,
                                                 float* __restrict__ a1es, float* __restrict__ a2es) {
    int pos = blockIdx.x * 256 + threadIdx.x;
    int e = eord[pos];
    float v[5];
    for (int j = 0; j < 5; j++) v[j] = ea[(size_t)e * 5 + j];
    float4 o;
    o.x = v[0]*M1[0]  + v[1]*M1[4]  + v[2]*M1[8]  + v[3]*M1[12] + v[4]*M1[16];
    o.y = v[0]*M1[1]  + v[1]*M1[5]  + v[2]*M1[9]  + v[3]*M1[13] + v[4]*M1[17];
    o.z = v[0]*M1[2]  + v[1]*M1[6]  + v[2]*M1[10] + v[3]*M1[14] + v[4]*M1[18];
    o.w = v[0]*M1[3]  + v[1]*M1[7]  + v[2]*M1[11] + v[3]*M1[15] + v[4]*M1[19];
    *(float4*)(a1es + (size_t)pos * 4) = o;
    a2es[pos] = v[0]*M2[0] + v[1]*M2[1] + v[2]*M2[2] + v[3]*M2[3] + v[4]*M2[4];
}

// ---------- register-blocked GEMM: vis = relu(roi @ roiW + b) ----------
__global__ __launch_bounds__(256) void k_vis(const float* __restrict__ A, const float* __restrict__ W,
                                             const float* __restrict__ bias, float* __restrict__ out) {
    __shared__ float At[64][68];
    __shared__ float Wl[64][68];
    int t = threadIdx.x;
    int n0 = blockIdx.x * 64;
    int cg = t & 15, rg = t >> 4;
    int sr = t >> 2, scs = (t & 3) * 16;
    float acc[4][4];
    for (int i = 0; i < 4; i++) for (int j = 0; j < 4; j++) acc[i][j] = 0.f;
    for (int kc = 0; kc < 4; kc++) {
        __syncthreads();
        const float* ap = A + (size_t)(n0 + sr) * 256 + kc * 64 + scs;
        float4 q0 = *(const float4*)ap, q1 = *(const float4*)(ap + 4);
        float4 q2 = *(const float4*)(ap + 8), q3 = *(const float4*)(ap + 12);
        At[scs + 0][sr] = q0.x;  At[scs + 1][sr] = q0.y;  At[scs + 2][sr] = q0.z;  At[scs + 3][sr] = q0.w;
        At[scs + 4][sr] = q1.x;  At[scs + 5][sr] = q1.y;  At[scs + 6][sr] = q1.z;  At[scs + 7][sr] = q1.w;
        At[scs + 8][sr] = q2.x;  At[scs + 9][sr] = q2.y;  At[scs + 10][sr] = q2.z; At[scs + 11][sr] = q2.w;
        At[scs + 12][sr] = q3.x; At[scs + 13][sr] = q3.y; At[scs + 14][sr] = q3.z; At[scs + 15][sr] = q3.w;
        const float* wp = W + (size_t)(kc * 64 + sr) * 64 + scs;
        *(float4*)&Wl[sr][scs + 0]  = *(const float4*)wp;
        *(float4*)&Wl[sr][scs + 4]  = *(const float4*)(wp + 4);
        *(float4*)&Wl[sr][scs + 8]  = *(const float4*)(wp + 8);
        *(float4*)&Wl[sr][scs + 12] = *(const float4*)(wp + 12);
        __syncthreads();
        for (int k = 0; k < 64; k++) {
            float4 a4 = *(const float4*)&At[k][rg * 4];
            float4 w4 = *(const float4*)&Wl[k][cg * 4];
            acc[0][0] += a4.x * w4.x; acc[0][1] += a4.x * w4.y; acc[0][2] += a4.x * w4.z; acc[0][3] += a4.x * w4.w;
            acc[1][0] += a4.y * w4.x; acc[1][1] += a4.y * w4.y; acc[1][2] += a4.y * w4.z; acc[1][3] += a4.y * w4.w;
            acc[2][0] += a4.z * w4.x; acc[2][1] += a4.z * w4.y; acc[2][2] += a4.z * w4.z; acc[2][3] += a4.z * w4.w;
            acc[3][0] += a4.w * w4.x; acc[3][1] += a4.w * w4.y; acc[3][2] += a4.w * w4.z; acc[3][3] += a4.w * w4.w;
        }
    }
    float4 bb = *(const float4*)(bias + cg * 4);
    for (int i = 0; i < 4; i++) {
        float4 o;
        o.x = fmaxf(acc[i][0] + bb.x, 0.f);
        o.y = fmaxf(acc[i][1] + bb.y, 0.f);
        o.z = fmaxf(acc[i][2] + bb.z, 0.f);
        o.w = fmaxf(acc[i][3] + bb.w, 0.f);
        *(float4*)(out + (size_t)(n0 + rg * 4 + i) * 64 + cg * 4) = o;
    }
}

// ---------- GEMM: h2 = out1(bf16) @ g2W -> bf16, fused a2s/a2d ----------
__global__ __launch_bounds__(256) void k_h2(const u16* __restrict__ A, const float* __restrict__ W,
                                            const float* __restrict__ as_, const float* __restrict__ ad_,
                                            u16* __restrict__ out, float* __restrict__ a2s,
                                            float* __restrict__ a2d) {
    __shared__ float At[64][68];
    __shared__ float Wl[64][68];
    int t = threadIdx.x;
    int n0 = blockIdx.x * 64;
    int cg = t & 15, rg = t >> 4;
    int sr = t >> 2, scs = (t & 3) * 16;
    float acc[4][4];
    for (int i = 0; i < 4; i++) for (int j = 0; j < 4; j++) acc[i][j] = 0.f;
    for (int kc = 0; kc < 4; kc++) {
        __syncthreads();
        const u16* ap = A + (size_t)(n0 + sr) * 256 + kc * 64 + scs;
        uint4 u0 = *(const uint4*)ap;
        uint4 u1 = *(const uint4*)(ap + 8);
        At[scs + 0][sr] = lo16(u0.x);  At[scs + 1][sr] = hi16(u0.x);
        At[scs + 2][sr] = lo16(u0.y);  At[scs + 3][sr] = hi16(u0.y);
        At[scs + 4][sr] = lo16(u0.z);  At[scs + 5][sr] = hi16(u0.z);
        At[scs + 6][sr] = lo16(u0.w);  At[scs + 7][sr] = hi16(u0.w);
        At[scs + 8][sr] = lo16(u1.x);  At[scs + 9][sr] = hi16(u1.x);
        At[scs + 10][sr] = lo16(u1.y); At[scs + 11][sr] = hi16(u1.y);
        At[scs + 12][sr] = lo16(u1.z); At[scs + 13][sr] = hi16(u1.z);
        At[scs + 14][sr] = lo16(u1.w); At[scs + 15][sr] = hi16(u1.w);
        const float* wp = W + (size_t)(kc * 64 + sr) * 64 + scs;
        *(float4*)&Wl[sr][scs + 0]  = *(const float4*)wp;
        *(float4*)&Wl[sr][scs + 4]  = *(const float4*)(wp + 4);
        *(float4*)&Wl[sr][scs + 8]  = *(const float4*)(wp + 8);
        *(float4*)&Wl[sr][scs + 12] = *(const float4*)(wp + 12);
        __syncthreads();
        for (int k = 0; k < 64; k++) {
            float4 a4 = *(const float4*)&At[k][rg * 4];
            float4 w4 = *(const float4*)&Wl[k][cg * 4];
            acc[0][0] += a4.x * w4.x; acc[0][1] += a4.x * w4.y; acc[0][2] += a4.x * w4.z; acc[0][3] += a4.x * w4.w;
            acc[1][0] += a4.y * w4.x; acc[1][1] += a4.y * w4.y; acc[1][2] += a4.y * w4.z; acc[1][3] += a4.y * w4.w;
            acc[2][0] += a4.z * w4.x; acc[2][1] += a4.z * w4.y; acc[2][2] += a4.z * w4.z; acc[2][3] += a4.z * w4.w;
            acc[3][0] += a4.w * w4.x; acc[3][1] += a4.w * w4.y; acc[3][2] += a4.w * w4.z; acc[3][3] += a4.w * w4.w;
        }
    }
    u32* outu = (u32*)out;
    for (int i = 0; i < 4; i++) {
        uint2 pk;
        pk.x = (u32)f2bf(acc[i][0]) | ((u32)f2bf(acc[i][1]) << 16);
        pk.y = (u32)f2bf(acc[i][2]) | ((u32)f2bf(acc[i][3]) << 16);
        *(uint2*)(outu + (size_t)(n0 + rg * 4 + i) * 32 + cg * 2) = pk;
    }
    float4 as4 = *(const float4*)(as_ + cg * 4);
    float4 ad4 = *(const float4*)(ad_ + cg * 4);
    #pragma unroll
    for (int i = 0; i < 4; i++) {
        float ps = acc[i][0] * as4.x + acc[i][1] * as4.y + acc[i][2] * as4.z + acc[i][3] * as4.w;
        float pd = acc[i][0] * ad4.x + acc[i][1] * ad4.y + acc[i][2] * ad4.z + acc[i][3] * ad4.w;
        for (int o = 1; o < 16; o <<= 1) { ps += __shfl_xor(ps, o, 64); pd += __shfl_xor(pd, o, 64); }
        if (cg == 0) {
            a2s[n0 + rg * 4 + i] = ps;
            a2d[n0 + rg * 4 + i] = pd;
        }
    }
}

// ---------- h1 = [x | vis] @ g1_W, fused a1s/a1d ----------
__global__ __launch_bounds__(256) void k_h1(const float* __restrict__ x, const float* __restrict__ vis,
                                            const float* __restrict__ g1W,
                                            const float* __restrict__ as_, const float* __restrict__ ad_,
                                            u16* __restrict__ h1, float* __restrict__ a1s,
                                            float* __restrict__ a1d) {
    __shared__ float At[77][36];
    __shared__ float Wl[77][132];
    int t = threadIdx.x, ch = blockIdx.y;
    int n0 = blockIdx.x * 32;
    int cg = t & 31, rg = t >> 5;
    for (int idx = t; idx < 9856; idx += 256) {
        int k = idx >> 7, c = idx & 127;
        Wl[k][c] = g1W[(size_t)k * 256 + ch * 128 + c];
    }
    for (int idx = t; idx < 2464; idx += 256) {
        int r = idx / 77, k = idx - r * 77;
        At[k][r] = (k < 13) ? x[(size_t)(n0 + r) * 13 + k] : vis[(size_t)(n0 + r) * 64 + (k - 13)];
    }
    __syncthreads();
    float acc[4][4];
    for (int i = 0; i < 4; i++) for (int j = 0; j < 4; j++) acc[i][j] = 0.f;
    for (int k = 0; k < 77; k++) {
        float4 a4 = *(const float4*)&At[k][rg * 4];
        float4 w4 = *(const float4*)&Wl[k][cg * 4];
        acc[0][0] += a4.x * w4.x; acc[0][1] += a4.x * w4.y; acc[0][2] += a4.x * w4.z; acc[0][3] += a4.x * w4.w;
        acc[1][0] += a4.y * w4.x; acc[1][1] += a4.y * w4.y; acc[1][2] += a4.y * w4.z; acc[1][3] += a4.y * w4.w;
        acc[2][0] += a4.z * w4.x; acc[2][1] += a4.z * w4.y; acc[2][2] += a4.z * w4.z; acc[2][3] += a4.z * w4.w;
        acc[3][0] += a4.w * w4.x; acc[3][1] += a4.w * w4.y; acc[3][2] += a4.w * w4.z; acc[3][3] += a4.w * w4.w;
    }
    for (int i = 0; i < 4; i++) {
        uint2 pk;
        pk.x = (u32)f2bf(acc[i][0]) | ((u32)f2bf(acc[i][1]) << 16);
        pk.y = (u32)f2bf(acc[i][2]) | ((u32)f2bf(acc[i][3]) << 16);
        *(uint2*)(h1 + (size_t)(n0 + rg * 4 + i) * 256 + ch * 128 + cg * 4) = pk;
    }
    // fused a1s/a1d: global head gh = ch*2 + (cg>>4); reduce over 16 lanes (cg&15)
    int gh = ch * 2 + (cg >> 4);
    int co = (cg & 15) * 4;   // within-head col offset of acc[.][0]
    float4 as4 = *(const float4*)(as_ + gh * 64 + co);
    float4 ad4 = *(const float4*)(ad_ + gh * 64 + co);
    #pragma unroll
    for (int i = 0; i < 4; i++) {
        float ps = acc[i][0] * as4.x + acc[i][1] * as4.y + acc[i][2] * as4.z + acc[i][3] * as4.w;
        float pd = acc[i][0] * ad4.x + acc[i][1] * ad4.y + acc[i][2] * ad4.z + acc[i][3] * ad4.w;
        for (int o = 1; o < 16; o <<= 1) { ps += __shfl_xor(ps, o, 64); pd += __shfl_xor(pd, o, 64); }
        if ((cg & 15) == 0) {
            int n = n0 + rg * 4 + i;
            a1s[n * 4 + gh] = ps;
            a1d[n * 4 + gh] = pd;
        }
    }
}

// ---------- GAT1 softmax: single pass, logits in w1, (m,inv) per (n,h) ----------
__global__ __launch_bounds__(256) void k_soft1(const int* __restrict__ row_ptr, const int* __restrict__ ssrc,
                                               const float* __restrict__ a1s, const float* __restrict__ a1d,
                                               const float* __restrict__ a1es, float* __restrict__ w1,
                                               float2* __restrict__ minv1) {
    int t = threadIdx.x;
    int wv = t >> 6, L = t & 63;
    int n = blockIdx.x * 4 + wv;
    int h = L >> 4, j = L & 15;
    int beg = row_ptr[n], deg = row_ptr[n + 1] - beg;
    if (deg == 0) return;
    float adn = a1d[n * 4 + h];
    float m = -3.0e38f, s = 0.f;
    for (int i = j; i < deg; i += 16) {
        int pos = beg + i;
        float l = a1s[ssrc[pos] * 4 + h] + adn + a1es[(size_t)pos * 4 + h];
        l = (l > 0.f) ? l : 0.2f * l;
        w1[(size_t)pos * 4 + h] = l;
        if (l > m) { s = s * __expf(m - l) + 1.f; m = l; }
        else       { s += __expf(l - m); }
    }
    for (int o = 1; o < 16; o <<= 1) {
        float mo = __shfl_xor(m, o, 64), so = __shfl_xor(s, o, 64);
        float M = fmaxf(m, mo);
        s = s * __expf(m - M) + so * __expf(mo - M);
        m = M;
    }
    if (j == 0) minv1[n * 4 + h] = make_float2(m, 1.f / (s + 1e-16f));
}

// ---------- GAT1 gather: logits + (m,inv), exp applied inline ----------
__global__ __launch_bounds__(256) void k_gath1(const int* __restrict__ row_ptr, const int* __restrict__ ssrc,
                                               const float* __restrict__ w1, const float2* __restrict__ minv1,
                                               const u16* __restrict__ h1,
                                               const float* __restrict__ bias, u16* __restrict__ out1) {
    int t = threadIdx.x;
    int wv = t >> 6, L = t & 63;
    int n = blockIdx.x * 4 + wv;
    int beg = row_ptr[n], deg = row_ptr[n + 1] - beg;
    int halfE = L >> 5;
    int L32 = L & 31;
    int hd = L32 >> 3;
    float2 mi = (deg > 0) ? minv1[n * 4 + hd] : make_float2(0.f, 0.f);
    float acc[8];
    #pragma unroll
    for (int j = 0; j < 8; j++) acc[j] = 0.f;
    int last = beg + deg - 1;
    for (int i = 0; i < deg; i += 8) {
        int iA = i + halfE, iB = i + 2 + halfE, iC = i + 4 + halfE, iD = i + 6 + halfE;
        bool vA = iA < deg, vB = iB < deg, vC = iC < deg, vD = iD < deg;
        int cA = vA ? beg + iA : last, cB = vB ? beg + iB : last;
        int cC = vC ? beg + iC : last, cD = vD ? beg + iD : last;
        int sA = ssrc[cA], sB = ssrc[cB], sC = ssrc[cC], sD = ssrc[cD];
        float lA = w1[(size_t)cA * 4 + hd];
        float lB = w1[(size_t)cB * 4 + hd];
        float lC = w1[(size_t)cC * 4 + hd];
        float lD = w1[(size_t)cD * 4 + hd];
        float wA = vA ? __expf(lA - mi.x) * mi.y : 0.f;
        float wB = vB ? __expf(lB - mi.x) * mi.y : 0.f;
        float wC = vC ? __expf(lC - mi.x) * mi.y : 0.f;
        float wD = vD ? __expf(lD - mi.x) * mi.y : 0.f;
        uint4 uA = *((const uint4*)(h1 + (size_t)sA * 256) + L32);
        uint4 uB = *((const uint4*)(h1 + (size_t)sB * 256) + L32);
        uint4 uC = *((const uint4*)(h1 + (size_t)sC * 256) + L32);
        uint4 uD = *((const uint4*)(h1 + (size_t)sD * 256) + L32);
        acc[0] += wA * lo16(uA.x) + wB * lo16(uB.x) + wC * lo16(uC.x) + wD * lo16(uD.x);
        acc[1] += wA * hi16(uA.x) + wB * hi16(uB.x) + wC * hi16(uC.x) + wD * hi16(uD.x);
        acc[2] += wA * lo16(uA.y) + wB * lo16(uB.y) + wC * lo16(uC.y) + wD * lo16(uD.y);
        acc[3] += wA * hi16(uA.y) + wB * hi16(uB.y) + wC * hi16(uC.y) + wD * hi16(uD.y);
        acc[4] += wA * lo16(uA.z) + wB * lo16(uB.z) + wC * lo16(uC.z) + wD * lo16(uD.z);
        acc[5] += wA * hi16(uA.z) + wB * hi16(uB.z) + wC * hi16(uC.z) + wD * hi16(uD.z);
        acc[6] += wA * lo16(uA.w) + wB * lo16(uB.w) + wC * lo16(uC.w) + wD * lo16(uD.w);
        acc[7] += wA * hi16(uA.w) + wB * hi16(uB.w) + wC * hi16(uC.w) + wD * hi16(uD.w);
    }
    #pragma unroll
    for (int j = 0; j < 8; j++) acc[j] += __shfl_xor(acc[j], 32, 64);
    if (halfE == 0) {
        float4 b0 = *(const float4*)(bias + 8 * L32);
        float4 b1 = *(const float4*)(bias + 8 * L32 + 4);
        uint4 pk;
        pk.x = (u32)f2bf(fmaxf(acc[0] + b0.x, 0.f)) | ((u32)f2bf(fmaxf(acc[1] + b0.y, 0.f)) << 16);
        pk.y = (u32)f2bf(fmaxf(acc[2] + b0.z, 0.f)) | ((u32)f2bf(fmaxf(acc[3] + b0.w, 0.f)) << 16);
        pk.z = (u32)f2bf(fmaxf(acc[4] + b1.x, 0.f)) | ((u32)f2bf(fmaxf(acc[5] + b1.y, 0.f)) << 16);
        pk.w = (u32)f2bf(fmaxf(acc[6] + b1.z, 0.f)) | ((u32)f2bf(fmaxf(acc[7] + b1.w, 0.f)) << 16);
        *((uint4*)(out1 + (size_t)n * 256) + L32) = pk;
    }
}

// ---------- GAT2 softmax: single pass ----------
__global__ __launch_bounds__(256) void k_soft2(const int* __restrict__ row_ptr, const int* __restrict__ ssrc,
                                               const float* __restrict__ a2s, const float* __restrict__ a2d,
                                               const float* __restrict__ a2es, float* __restrict__ w2,
                                               float2* __restrict__ minv2) {
    int t = threadIdx.x;
    int wv = t >> 6, L = t & 63;
    int g = L >> 4, j = L & 15;
    int n = blockIdx.x * 16 + wv * 4 + g;
    int beg = row_ptr[n], deg = row_ptr[n + 1] - beg;
    if (deg == 0) return;
    float adn = a2d[n];
    float m = -3.0e38f, s = 0.f;
    for (int i = j; i < deg; i += 16) {
        int pos = beg + i;
        float l = a2s[ssrc[pos]] + adn + a2es[pos];
        l = (l > 0.f) ? l : 0.2f * l;
        w2[pos] = l;
        if (l > m) { s = s * __expf(m - l) + 1.f; m = l; }
        else       { s += __expf(l - m); }
    }
    for (int o = 1; o < 16; o <<= 1) {
        float mo = __shfl_xor(m, o, 64), so = __shfl_xor(s, o, 64);
        float M = fmaxf(m, mo);
        s = s * __expf(m - M) + so * __expf(mo - M);
        m = M;
    }
    if (j == 0) minv2[n] = make_float2(m, 1.f / (s + 1e-16f));
}

// ---------- GAT2 gather ----------
__global__ __launch_bounds__(256) void k_gath2(const int* __restrict__ row_ptr, const int* __restrict__ ssrc,
                                               const float* __restrict__ w2, const float2* __restrict__ minv2,
                                               const u16* __restrict__ h2b,
                                               const float* __restrict__ bias, float* __restrict__ hfin) {
    int t = threadIdx.x;
    int wv = t >> 6, L = t & 63;
    int n = blockIdx.x * 4 + wv;
    int beg = row_ptr[n], deg = row_ptr[n + 1] - beg;
    int halfE = L >> 5;
    int L32 = L & 31;
    float2 mi = (deg > 0) ? minv2[n] : make_float2(0.f, 0.f);
    float a0 = 0.f, a1v = 0.f;
    int last = beg + deg - 1;
    const u32* h2u = (const u32*)h2b;
    for (int i = 0; i < deg; i += 8) {
        int iA = i + halfE, iB = i + 2 + halfE, iC = i + 4 + halfE, iD = i + 6 + halfE;
        bool vA = iA < deg, vB = iB < deg, vC = iC < deg, vD = iD < deg;
        int cA = vA ? beg + iA : last, cB = vB ? beg + iB : last;
        int cC = vC ? beg + iC : last, cD = vD ? beg + iD : last;
        int sA = ssrc[cA], sB = ssrc[cB], sC = ssrc[cC], sD = ssrc[cD];
        float lA = w2[cA], lB = w2[cB], lC = w2[cC], lD = w2[cD];
        float wA = vA ? __expf(lA - mi.x) * mi.y : 0.f;
        float wB = vB ? __expf(lB - mi.x) * mi.y : 0.f;
        float wC = vC ? __expf(lC - mi.x) * mi.y : 0.f;
        float wD = vD ? __expf(lD - mi.x) * mi.y : 0.f;
        u32 uA = h2u[(size_t)sA * 32 + L32];
        u32 uB = h2u[(size_t)sB * 32 + L32];
        u32 uC = h2u[(size_t)sC * 32 + L32];
        u32 uD = h2u[(size_t)sD * 32 + L32];
        a0  += wA * lo16(uA) + wB * lo16(uB) + wC * lo16(uC) + wD * lo16(uD);
        a1v += wA * hi16(uA) + wB * hi16(uB) + wC * hi16(uC) + wD * hi16(uD);
    }
    a0  += __shfl_xor(a0, 32, 64);
    a1v += __shfl_xor(a1v, 32, 64);
    if (halfE == 0) {
        float2 o;
        o.x = a0  + bias[2 * L32];
        o.y = a1v + bias[2 * L32 + 1];
        *(float2*)(hfin + (size_t)n * 64 + 2 * L32) = o;
    }
}

// ---------- pooling + classifier ----------
__global__ __launch_bounds__(64) void k_pool(const int* __restrict__ bvec, const float* __restrict__ hf,
                                             const float* gateW, const float* gateb,
                                             const float* __restrict__ scene,
                                             const float* c1W, const float* c1b,
                                             const float* c2W, const float* c2b,
                                             float* __restrict__ outp) {
    int b = blockIdx.x, lane = threadIdx.x;
    __shared__ float gwl[64], se[64], comb[192], hid[64];
    gwl[lane] = gateW[lane];
    __syncthreads();
    int s0, s1;
    { int lo = 0, hi = N_NODES; while (lo < hi) { int mid = (lo + hi) >> 1; if (bvec[mid] < b) lo = mid + 1; else hi = mid; } s0 = lo; }
    { int lo = 0, hi = N_NODES; while (lo < hi) { int mid = (lo + hi) >> 1; if (bvec[mid] < b + 1) lo = mid + 1; else hi = mid; } s1 = lo; }
    float gb = gateb[0];
    float m = -3.0e38f, ssum = 0.f, acc = 0.f;
    for (int cs = s0; cs < s1; cs += 64) {
        int cnt = min(64, s1 - cs);
        float l = -3.0e38f;
        if (lane < cnt) {
            int n = cs + lane;
            float d = 0.f;
            for (int i = 0; i < 64; i++) d += hf[(size_t)n * 64 + i] * gwl[i];
            l = d + gb;
        }
        float cm = wmax(l);
        float newm = fmaxf(m, cm);
        float rsc = __expf(m - newm);
        float e = (lane < cnt) ? __expf(l - newm) : 0.f;
        float es = wsum(e);
        ssum = ssum * rsc + es;
        se[lane] = e;
        __syncthreads();
        float a2 = 0.f;
        for (int i = 0; i < cnt; i++) a2 += se[i] * hf[(size_t)(cs + i) * 64 + lane];
        acc = acc * rsc + a2;
        __syncthreads();
        m = newm;
    }
    float rel = acc / (ssum + 1e-16f);
    comb[lane] = scene[b * 128 + lane];
    comb[64 + lane] = scene[b * 128 + 64 + lane];
    comb[128 + lane] = rel;
    __syncthreads();
    float hj = 0.f;
    for (int k = 0; k < 192; k++) hj += comb[k] * c1W[k * 64 + lane];
    hj += c1b[lane];
    hid[lane] = fmaxf(hj, 0.f);
    __syncthreads();
    if (lane < 3) {
        float o = 0.f;
        for (int k = 0; k < 64; k++) o += hid[k] * c2W[k * 3 + lane];
        o += c2b[lane];
        outp[b * 3 + lane] = o;
    }
}

extern "C" void kernel_launch(void* const* d_in, const int* in_sizes, int n_in,
                              void* d_out, int out_size, void* d_ws, size_t ws_size,
                              hipStream_t stream) {
    (void)in_sizes; (void)n_in; (void)out_size; (void)ws_size;
    const float* gf     = (const float*)d_in[0];
    const float* x      = (const float*)d_in[1];
    const float* roi    = (const float*)d_in[2];
    const int*   ei     = (const int*)d_in[3];
    const float* ea     = (const float*)d_in[4];
    const int*   bvec   = (const int*)d_in[5];
    const float* roiW   = (const float*)d_in[6];
    const float* roib   = (const float*)d_in[7];
    const float* sceneW = (const float*)d_in[8];
    const float* sceneb = (const float*)d_in[9];
    const float* g1W    = (const float*)d_in[10];
    const float* g1as   = (const float*)d_in[11];
    const float* g1ad   = (const float*)d_in[12];
    const float* g1We   = (const float*)d_in[13];
    const float* g1ae   = (const float*)d_in[14];
    const float* g1b    = (const float*)d_in[15];
    const float* g2W    = (const float*)d_in[16];
    const float* g2as   = (const float*)d_in[17];
    const float* g2ad   = (const float*)d_in[18];
    const float* g2We   = (const float*)d_in[19];
    const float* g2ae   = (const float*)d_in[20];
    const float* g2b    = (const float*)d_in[21];
    const float* gateW  = (const float*)d_in[22];
    const float* gateb  = (const float*)d_in[23];
    const float* c1W    = (const float*)d_in[24];
    const float* c1b    = (const float*)d_in[25];
    const float* c2W    = (const float*)d_in[26];
    const float* c2b    = (const float*)d_in[27];

    char* w = (char*)d_ws;
    size_t o = 0;
    auto nxt = [&](size_t bytes) -> char* {
        char* p = w + o;
        o += (bytes + 255) & ~(size_t)255;
        return p;
    };
    float* scene  = (float*)nxt((size_t)NB * 128 * 4);
    float* M1     = (float*)nxt(80);
    float* M2     = (float*)nxt(32);
    int* cnt      = (int*)nxt((size_t)N_NODES * 4);
    int* pre      = (int*)nxt((size_t)N_NODES * 4);
    int* bsum     = (int*)nxt(64 * 4);
    int* row_ptr  = (int*)nxt((size_t)(N_NODES + 1) * 4);
    int* coarse   = (int*)nxt(256 * 4);
    u32* bpack    = (u32*)nxt((size_t)N_EDGES * 4);
    int* bsrc     = (int*)nxt((size_t)N_EDGES * 4);
    int* eord     = (int*)nxt((size_t)N_EDGES * 4);
    int* ssrc     = (int*)nxt((size_t)N_EDGES * 4);
    float* a1es   = (float*)nxt((size_t)N_EDGES * 16);
    float* a2es   = (float*)nxt((size_t)N_EDGES * 4);
    float* visbuf = (float*)nxt((size_t)N_NODES * 64 * 4);   // vis, later aliased as w2
    u16* h1       = (u16*)nxt((size_t)N_NODES * 256 * 2);
    u16* out1     = (u16*)nxt((size_t)N_NODES * 256 * 2);
    float* w1buf  = (float*)nxt((size_t)N_EDGES * 16);       // w1 logits, later aliased as h2(bf16)
    float* hfin   = (float*)nxt((size_t)N_NODES * 64 * 4);
    float* a1s    = (float*)nxt((size_t)N_NODES * 16);
    float* a1d    = (float*)nxt((size_t)N_NODES * 16);
    float* a2s    = (float*)nxt((size_t)N_NODES * 4);
    float* a2d    = (float*)nxt((size_t)N_NODES * 4);
    float2* minv1 = (float2*)nxt((size_t)N_NODES * 4 * 8);
    float2* minv2 = (float2*)nxt((size_t)N_NODES * 8);

    float* vis = visbuf;
    float* w2  = visbuf;      // vis dead after k_h1; w2 (logits) written by k_soft2 (later)
    float* w1  = w1buf;
    u16*   h2b = (u16*)w1buf; // w1 dead after k_gath1; h2(bf16) written by k_h2 (later)

    hipMemsetAsync(cnt, 0, (size_t)N_NODES * 4, stream);
    k_prep<<<1, 32, 0, stream>>>(g1We, g1ae, g2We, g2ae, M1, M2);
    k_scene<<<(NB * 128) / 256, 256, 0, stream>>>(gf, sceneW, sceneb, scene);
    k_hist<<<N_EDGES / 256, 256, 0, stream>>>(ei, cnt);
    k_scan_blk<<<64, 256, 0, stream>>>(cnt, pre, bsum);
    k_scan_top<<<1, 64, 0, stream>>>(bsum);
    k_scan_fix<<<N_NODES / 256, 256, 0, stream>>>(pre, bsum, row_ptr, coarse);
    k_bucket<<<256, 256, 0, stream>>>(ei, coarse, bpack, bsrc);
    k_sortb<<<256, 256, 0, stream>>>(bpack, bsrc, row_ptr, eord, ssrc);
    k_payload<<<N_EDGES / 256, 256, 0, stream>>>(eord, ea, M1, M2, a1es, a2es);
    k_vis<<<N_NODES / 64, 256, 0, stream>>>(roi, roiW, roib, vis);
    k_h1<<<dim3(N_NODES / 32, 2), 256, 0, stream>>>(x, vis, g1W, g1as, g1ad, h1, a1s, a1d);
    k_soft1<<<N_NODES / 4, 256, 0, stream>>>(row_ptr, ssrc, a1s, a1d, a1es, w1, minv1);
    k_gath1<<<N_NODES / 4, 256, 0, stream>>>(row_ptr, ssrc, w1, minv1, h1, g1b, out1);
    k_h2<<<N_NODES / 64, 256, 0, stream>>>(out1, g2W, g2as, g2ad, h2b, a2s, a2d);
    k_soft2<<<N_NODES / 16, 256, 0, stream>>>(row_ptr, ssrc, a2s, a2d, a2es, w2, minv2);
    k_gath2<<<N_NODES / 4, 256, 0, stream>>>(row_ptr, ssrc, w2, minv2, h2b, g2b, hfin);
    k_pool<<<NB, 64, 0, stream>>>(bvec, hfin, gateW, gateb, scene, c1W, c1b, c2W, c2b, (float*)d_out);
}